// Round 1
// baseline (9866.784 us; speedup 1.0000x reference)
//
#include <hip/hip_runtime.h>
#include <math.h>

// ---------------------------------------------------------------------------
// f32 correctness-first baseline. Structure:
//  k_embed -> 32 x k_step (bi-LSTM, h parity double-buffered) -> k_qnorm
//  k_sqpart/k_invnorm -> k_conv3<1026,0> -> bnstats/bnapply
//  -> [k_conv1x1 -> k_conv3<128,1> -> bnstats -> bnapply_add] x2
// Workspace: ~47 MB floats.
// ---------------------------------------------------------------------------

namespace {

constexpr int S_ = 32, B_ = 128, E_ = 300, H_ = 1024, P_ = 196, OC_ = 128;

__device__ __forceinline__ float sigm(float x){ return 1.0f/(1.0f + expf(-x)); }
// reference: c0 = ((y*14+x)/14.0 - 7)/7 (true division!), c1 = (x - 7)/7
__device__ __forceinline__ float c0f(int p){ return ((float)p/14.0f - 7.0f)/7.0f; }
__device__ __forceinline__ float c1f(int p){ return ((float)(p%14) - 7.0f)/7.0f; }

// ---------------- embedding: x[s][b][e] --------------------------------------
__global__ void k_embed(const int* __restrict__ que, const float* __restrict__ emb,
                        float* __restrict__ x){
  int idx = blockIdx.x*256 + threadIdx.x;
  if (idx >= S_*B_*E_) return;
  int e = idx % E_; int sb = idx / E_; int b = sb % B_; int s = sb / B_;
  int t = que[b*S_ + s];
  x[idx] = (t == 0) ? 0.0f : emb[t*E_ + e];
}

// ---------------- one LSTM step, both directions -----------------------------
// grid (128 unit-tiles of 8, 2 dirs), block 256.
// Block computes g tile [128 rows(B) x 32 cols(8 units x 4 gates)], K=1324
// (300 x-part folded in + 1024 h-part), then applies gate math for its units.
__launch_bounds__(256)
__global__ void k_step(const float* __restrict__ x,
                       const float* __restrict__ wihf, const float* __restrict__ whhf,
                       const float* __restrict__ bihf, const float* __restrict__ bhhf,
                       const float* __restrict__ wihb, const float* __restrict__ whhb,
                       const float* __restrict__ bihb, const float* __restrict__ bhhb,
                       const float* __restrict__ hin, float* __restrict__ hout,
                       float* __restrict__ cst, float* __restrict__ Q, int s){
  const int dir = blockIdx.y;
  const int u0  = blockIdx.x * 8;
  const float* wih = dir ? wihb : wihf;
  const float* whh = dir ? whhb : whhf;
  const float* bih = dir ? bihb : bihf;
  const float* bhh = dir ? bhhb : bhhf;
  const int xs = dir ? (S_-1-s) : s;
  const float* xrow = x + (size_t)xs*B_*E_;
  const float* hi = hin  + (size_t)dir*B_*H_;
  float*       ho = hout + (size_t)dir*B_*H_;
  float*       cc = cst  + (size_t)dir*B_*H_;

  __shared__ float sA[8][136];   // [k][m], padded
  __shared__ float sB[8][33];    // [k][n]  n: u = n&7, gate = n>>3
  __shared__ float sG[128][33];  // gate-tile for recombination

  const int tid = threadIdx.x;
  const int tr = tid >> 4, tc = tid & 15;   // thread tile: 8 rows x 2 cols
  float acc[8][2];
  #pragma unroll
  for (int i = 0; i < 8; ++i){ acc[i][0] = 0.f; acc[i][1] = 0.f; }

  const int nn = tid >> 3, kk = tid & 7;          // B-staging assignment
  const int ju = (nn >> 3)*1024 + u0 + (nn & 7);  // weight row for col nn

  for (int k0 = 0; k0 < 1324; k0 += 8){
    __syncthreads();
    #pragma unroll
    for (int i = 0; i < 4; ++i){            // stage A: 128x8
      int t2 = tid + i*256;
      int m = t2 >> 3, k = t2 & 7, kg = k0 + k;
      float v = 0.f;
      if (kg < 300)       v = xrow[m*E_ + kg];
      else if (kg < 1324) v = hi[m*H_ + (kg-300)];
      sA[k][m] = v;
    }
    {                                       // stage B: 32x8
      int kg = k0 + kk;
      float v = 0.f;
      if (kg < 300)       v = wih[ju*300 + kg];
      else if (kg < 1324) v = whh[ju*1024 + (kg-300)];
      sB[kk][nn] = v;
    }
    __syncthreads();
    #pragma unroll
    for (int k = 0; k < 8; ++k){
      float b0 = sB[k][tc*2], b1 = sB[k][tc*2+1];
      #pragma unroll
      for (int i = 0; i < 8; ++i){
        float a = sA[k][tr*8+i];
        acc[i][0] += a*b0; acc[i][1] += a*b1;
      }
    }
  }
  __syncthreads();
  #pragma unroll
  for (int i = 0; i < 8; ++i){
    sG[tr*8+i][tc*2]   = acc[i][0];
    sG[tr*8+i][tc*2+1] = acc[i][1];
  }
  __syncthreads();
  #pragma unroll
  for (int t = 0; t < 4; ++t){
    int w2 = tid + t*256;                 // 1024 tasks: 128 rows x 8 units
    int m = w2 >> 3, u = w2 & 7;
    int ug = u0 + u;
    float gi = sG[m][u]    + bih[ug]      + bhh[ug];
    float gf = sG[m][8+u]  + bih[1024+ug] + bhh[1024+ug];
    float gg = sG[m][16+u] + bih[2048+ug] + bhh[2048+ug];
    float go = sG[m][24+u] + bih[3072+ug] + bhh[3072+ug];
    float cold = cc[m*H_ + ug];
    float cn = sigm(gf)*cold + sigm(gi)*tanhf(gg);
    float hn = sigm(go)*tanhf(cn);
    cc[m*H_ + ug] = cn;
    ho[m*H_ + ug] = hn;
    int qs = dir ? (S_-1-s) : s;          // hb is re-reversed
    Q[((size_t)qs*B_ + m)*2048 + dir*1024 + ug] = hn;
  }
}

// ---------------- qenc L2-normalize (in-place) + enc -------------------------
__global__ void k_qnorm(float* __restrict__ Q, float* __restrict__ enc){
  int sb = blockIdx.x;             // s*128+b
  int s = sb >> 7, b = sb & 127;
  float* row = Q + (size_t)sb*2048;
  int tid = threadIdx.x;
  float v[8]; float ss = 0.f;
  #pragma unroll
  for (int i = 0; i < 8; ++i){ v[i] = row[tid*8+i]; ss += v[i]*v[i]; }
  __shared__ float red[256];
  red[tid] = ss; __syncthreads();
  for (int st = 128; st; st >>= 1){
    if (tid < st) red[tid] += red[tid+st];
    __syncthreads();
  }
  float inv = 1.0f / fmaxf(sqrtf(red[0]), 1e-12f);
  #pragma unroll
  for (int i = 0; i < 8; ++i){
    float q = v[i]*inv;
    row[tid*8+i] = q;
    if (s == S_-1) enc[(size_t)b*2048 + tid*8 + i] = q;
  }
}

// ---------------- per-pixel channel sumsq of img (partial over 256 ch) -------
__global__ void k_sqpart(const float* __restrict__ img, float* __restrict__ part){
  int b = blockIdx.x, cq = blockIdx.y;
  int t = threadIdx.x;
  if (t >= P_) return;
  const float* base = img + ((size_t)b*1024 + cq*256)*P_ + t;
  float s = 0.f;
  #pragma unroll 4
  for (int c = 0; c < 256; ++c){ float v = base[c*P_]; s += v*v; }
  part[((size_t)b*4 + cq)*P_ + t] = s;
}

__global__ void k_invnorm(const float* __restrict__ part, float* __restrict__ inv){
  int i = blockIdx.x*256 + threadIdx.x;
  if (i >= B_*P_) return;
  int b = i / P_, p = i % P_;
  float s = part[(b*4+0)*P_+p] + part[(b*4+1)*P_+p]
          + part[(b*4+2)*P_+p] + part[(b*4+3)*P_+p];
  inv[i] = 1.0f / fmaxf(sqrtf(s), 1e-12f);
}

// ---------------- 3x3 conv, pad 1, 14x14 -------------------------------------
// MODE 0: input = img * inv_norm, channels 1024,1025 are coords (CIN=1026)
// MODE 1: input = plain buffer [B][CIN][196]
// grid (2 o-tiles of 64, 128 b), block 256: 16 o-lanes(4 o) x 16 rows(14 used)
template<int CIN, int MODE>
__launch_bounds__(256)
__global__ void k_conv3(const float* __restrict__ in, const float* __restrict__ inv,
                        const float* __restrict__ w, const float* __restrict__ bias,
                        float* __restrict__ out){
  const int o0 = blockIdx.x * 64;
  const int b  = blockIdx.y;
  const int tid = threadIdx.x;
  const int olane = tid & 15;
  const int prow  = tid >> 4;       // image row y (0..13 active)

  __shared__ float sIn[8][16][16];  // [c][y+1][x+1], zero-padded halo
  __shared__ float sW[64][73];      // [o_local][c*9+k], pad to 73

  float acc[4][14];
  #pragma unroll
  for (int i = 0; i < 4; ++i){
    float bz = bias[o0 + olane*4 + i];
    #pragma unroll
    for (int xx = 0; xx < 14; ++xx) acc[i][xx] = bz;
  }

  for (int c0 = 0; c0 < CIN; c0 += 8){
    const int CH = (CIN - c0 < 8) ? (CIN - c0) : 8;
    __syncthreads();
    for (int i = tid; i < CH*256; i += 256){
      int cc = i >> 8, r = (i >> 4) & 15, xx = i & 15;
      int y = r - 1, xq = xx - 1;
      float v = 0.f;
      if ((unsigned)y < 14u && (unsigned)xq < 14u){
        int p = y*14 + xq, c = c0 + cc;
        if (MODE == 0){
          if (c < 1024)      v = in[((size_t)b*1024 + c)*P_ + p] * inv[b*P_ + p];
          else if (c == 1024) v = c0f(p);
          else                v = c1f(p);
        } else {
          v = in[((size_t)b*CIN + c)*P_ + p];
        }
      }
      sIn[cc][r][xx] = v;
    }
    for (int i = tid; i < 64*CH*9; i += 256){
      int ol = i / (CH*9), rem = i % (CH*9);
      int cc = rem / 9, k = rem % 9;
      sW[ol][cc*9 + k] = w[((size_t)(o0+ol)*CIN + (c0+cc))*9 + k];
    }
    __syncthreads();
    if (prow < 14){
      for (int cc = 0; cc < CH; ++cc){
        float wreg[4][9];
        #pragma unroll
        for (int i = 0; i < 4; ++i)
          #pragma unroll
          for (int k = 0; k < 9; ++k)
            wreg[i][k] = sW[olane*4+i][cc*9+k];
        #pragma unroll
        for (int dy = 0; dy < 3; ++dy){
          float rr[16];
          #pragma unroll
          for (int xx = 0; xx < 16; ++xx) rr[xx] = sIn[cc][prow+dy][xx];
          #pragma unroll
          for (int xx = 0; xx < 14; ++xx)
            #pragma unroll
            for (int i = 0; i < 4; ++i)
              #pragma unroll
              for (int dx = 0; dx < 3; ++dx)
                acc[i][xx] += rr[xx+dx] * wreg[i][dy*3+dx];
        }
      }
    }
  }
  if (prow < 14){
    #pragma unroll
    for (int i = 0; i < 4; ++i){
      int o = o0 + olane*4 + i;
      #pragma unroll
      for (int xx = 0; xx < 14; ++xx)
        out[((size_t)b*OC_ + o)*P_ + prow*14 + xx] = acc[i][xx];
    }
  }
}

// ---------------- BN training-mode stats: mean + invstd per channel ----------
__global__ void k_bnstats(const float* __restrict__ t, float* __restrict__ stats){
  int o = blockIdx.x;
  int tid = threadIdx.x;
  float s = 0.f, s2 = 0.f;
  for (int i = tid; i < B_*P_; i += 256){
    int b = i / P_, p = i % P_;
    float v = t[((size_t)b*OC_ + o)*P_ + p];
    s += v; s2 += v*v;
  }
  __shared__ float r1[256], r2[256];
  r1[tid] = s; r2[tid] = s2; __syncthreads();
  for (int st = 128; st; st >>= 1){
    if (tid < st){ r1[tid] += r1[tid+st]; r2[tid] += r2[tid+st]; }
    __syncthreads();
  }
  if (tid == 0){
    float n = (float)(B_*P_);
    float m = r1[0] / n;
    float var = r2[0] / n - m*m;
    stats[o*2]   = m;
    stats[o*2+1] = rsqrtf(var + 1e-5f);
  }
}

// ---------------- BN apply + relu (+ optional residual add) ------------------
template<bool ADD>
__global__ void k_bnapply(const float* __restrict__ t, const float* __restrict__ stats,
                          const float* __restrict__ g, const float* __restrict__ bb,
                          const float* __restrict__ addsrc, float* __restrict__ out){
  int idx = blockIdx.x*256 + threadIdx.x;
  if (idx >= B_*OC_*P_) return;
  int o = (idx / P_) % OC_;
  float m = stats[o*2], is = stats[o*2+1];
  float v = g[o]*(t[idx]-m)*is + bb[o];
  v = fmaxf(v, 0.f);
  if (ADD) v += addsrc[idx];
  out[idx] = v;
}

// ---------------- 1x1 conv over [v(128) | coord(2)] + bias + relu ------------
// grid (128 b, 2 o-tiles of 64), block 256: 64 o-lanes x 4 pixel-groups of 49
__launch_bounds__(256)
__global__ void k_conv1x1(const float* __restrict__ vin, const float* __restrict__ w,
                          const float* __restrict__ bias, float* __restrict__ out){
  const int b  = blockIdx.x;
  const int o0 = blockIdx.y * 64;
  const int tid = threadIdx.x;
  const int olane = tid & 63, pg = tid >> 6;
  const int o = o0 + olane;

  __shared__ float sV[32][196];
  __shared__ float sW[64][33];

  float acc[49];
  #pragma unroll
  for (int p = 0; p < 49; ++p) acc[p] = 0.f;

  for (int ch = 0; ch < 128; ch += 32){
    __syncthreads();
    for (int i = tid; i < 32*196; i += 256){
      int c = i / 196, p = i % 196;
      sV[c][p] = vin[((size_t)b*128 + ch + c)*P_ + p];
    }
    for (int i = tid; i < 64*32; i += 256){
      int ol = i >> 5, c = i & 31;
      sW[ol][c] = w[(size_t)(o0+ol)*130 + ch + c];
    }
    __syncthreads();
    for (int c = 0; c < 32; ++c){
      float wv = sW[olane][c];
      #pragma unroll
      for (int p = 0; p < 49; ++p) acc[p] += sV[c][pg*49 + p] * wv;
    }
  }
  float w0 = w[(size_t)o*130 + 128], w1 = w[(size_t)o*130 + 129], bz = bias[o];
  #pragma unroll
  for (int p = 0; p < 49; ++p){
    int pp = pg*49 + p;
    float v = acc[p] + w0*c0f(pp) + w1*c1f(pp) + bz;
    out[((size_t)b*128 + o)*P_ + pp] = fmaxf(v, 0.f);
  }
}

} // namespace

// ---------------------------------------------------------------------------
extern "C" void kernel_launch(void* const* d_in, const int* in_sizes, int n_in,
                              void* d_out, int out_size, void* d_ws, size_t ws_size,
                              hipStream_t stream){
  (void)in_sizes; (void)n_in; (void)out_size; (void)ws_size;
  const int*   que  = (const int*)  d_in[0];
  const float* img  = (const float*)d_in[1];
  const float* emb  = (const float*)d_in[2];
  const float* wihf = (const float*)d_in[3];
  const float* whhf = (const float*)d_in[4];
  const float* bihf = (const float*)d_in[5];
  const float* bhhf = (const float*)d_in[6];
  const float* wihb = (const float*)d_in[7];
  const float* whhb = (const float*)d_in[8];
  const float* bihb = (const float*)d_in[9];
  const float* bhhb = (const float*)d_in[10];
  const float* convw = (const float*)d_in[11];
  const float* convb = (const float*)d_in[12];
  const float* bng  = (const float*)d_in[13];
  const float* bnb  = (const float*)d_in[14];
  const float* r1c1w = (const float*)d_in[15];
  const float* r1c1b = (const float*)d_in[16];
  const float* r1c2w = (const float*)d_in[17];
  const float* r1c2b = (const float*)d_in[18];
  const float* r1bng = (const float*)d_in[19];
  const float* r1bnb = (const float*)d_in[20];
  const float* r2c1w = (const float*)d_in[21];
  const float* r2c1b = (const float*)d_in[22];
  const float* r2c2w = (const float*)d_in[23];
  const float* r2c2b = (const float*)d_in[24];
  const float* r2bng = (const float*)d_in[25];
  const float* r2bnb = (const float*)d_in[26];

  float* out  = (float*)d_out;
  float* enc  = out;                        // 128*2048
  float* Q    = out + 262144;               // 32*128*2048 (raw h then normalized)
  float* vout = out + 262144 + 8388608;     // 128*128*196

  float* ws     = (float*)d_ws;             // total ~11.8M floats (~47 MB)
  float* x      = ws;                       // 32*128*300   = 1228800
  float* hstate = x + 1228800;              // 2(par)*2(dir)*128*1024 = 524288
  float* cstate = hstate + 524288;          // 2*128*1024   = 262144
  float* part   = cstate + 262144;          // 128*4*196    = 100352
  float* invn   = part + 100352;            // 128*196      = 25088
  float* bufA   = invn + 25088;             // 128*128*196  = 3211264
  float* bufB   = bufA + 3211264;
  float* bufC   = bufB + 3211264;
  float* stats  = bufC + 3211264;           // 128*2

  const int NE = 3211264;  // elements of a [B][128][196] buffer

  // zero h (both parities) and c state
  hipMemsetAsync(hstate, 0, (size_t)(524288 + 262144)*sizeof(float), stream);

  k_embed<<<(S_==32 ? (1228800+255)/256 : 0), 256, 0, stream>>>(que, emb, x);

  for (int s = 0; s < 32; ++s){
    float* hin  = hstate + (size_t)(s & 1)*262144;
    float* hout = hstate + (size_t)((s & 1)^1)*262144;
    k_step<<<dim3(128,2), 256, 0, stream>>>(x, wihf, whhf, bihf, bhhf,
                                            wihb, whhb, bihb, bhhb,
                                            hin, hout, cstate, Q, s);
  }
  k_qnorm<<<4096, 256, 0, stream>>>(Q, enc);

  k_sqpart<<<dim3(128,4), 256, 0, stream>>>(img, part);
  k_invnorm<<<(25088+255)/256, 256, 0, stream>>>(part, invn);

  // main conv + BN + relu
  k_conv3<1026,0><<<dim3(2,128), 256, 0, stream>>>(img, invn, convw, convb, bufA);
  k_bnstats<<<128, 256, 0, stream>>>(bufA, stats);
  k_bnapply<false><<<(NE+255)/256, 256, 0, stream>>>(bufA, stats, bng, bnb, bufA, bufA);

  // res block 1: bufA(v) -> bufB(v1) -> bufC(conv2) -> bufA(v2+v1)
  k_conv1x1<<<dim3(128,2), 256, 0, stream>>>(bufA, r1c1w, r1c1b, bufB);
  k_conv3<128,1><<<dim3(2,128), 256, 0, stream>>>(bufB, invn, r1c2w, r1c2b, bufC);
  k_bnstats<<<128, 256, 0, stream>>>(bufC, stats);
  k_bnapply<true><<<(NE+255)/256, 256, 0, stream>>>(bufC, stats, r1bng, r1bnb, bufB, bufA);

  // res block 2: bufA -> bufB(v1) -> bufC -> vout
  k_conv1x1<<<dim3(128,2), 256, 0, stream>>>(bufA, r2c1w, r2c1b, bufB);
  k_conv3<128,1><<<dim3(2,128), 256, 0, stream>>>(bufB, invn, r2c2w, r2c2b, bufC);
  k_bnstats<<<128, 256, 0, stream>>>(bufC, stats);
  k_bnapply<true><<<(NE+255)/256, 256, 0, stream>>>(bufC, stats, r2bng, r2bnb, bufB, vout);
}

// Round 2
// 2530.370 us; speedup vs baseline: 3.8993x; 3.8993x over previous
//
#include <hip/hip_runtime.h>
#include <hip/hip_bf16.h>
#include <math.h>

// ---------------------------------------------------------------------------
// R2: LSTM -> bf16 MFMA per-step GEMM (K = 320(x,pad) + 1024(h)), gates fused.
//     conv3 stays f32 VALU but z-split over K halves (2x blocks, partial sums
//     reduced inside bnstats/bnapply).
// ---------------------------------------------------------------------------

namespace {

constexpr int S_ = 32, B_ = 128, H_ = 1024, P_ = 196, OC_ = 128;
constexpr int NE = B_ * OC_ * P_;        // 3,211,264 elems of a [B][128][196] slab
constexpr int KX = 320;                  // padded x-K (300 -> 320)

typedef __attribute__((ext_vector_type(8))) short short8v;
typedef __attribute__((ext_vector_type(4))) float f32x4;
#define MFMA16(a, b, c) __builtin_amdgcn_mfma_f32_16x16x32_bf16((a), (b), (c), 0, 0, 0)

__device__ __forceinline__ float sigm(float x){ return 1.0f/(1.0f + expf(-x)); }
__device__ __forceinline__ float c0f(int p){ return ((float)p/14.0f - 7.0f)/7.0f; }
__device__ __forceinline__ float c1f(int p){ return ((float)(p%14) - 7.0f)/7.0f; }
__device__ __forceinline__ unsigned short f2bf(float x){
  __hip_bfloat16 h = __float2bfloat16(x);
  return *reinterpret_cast<unsigned short*>(&h);
}

// ---------------- weight convert f32 -> bf16, K-padded -----------------------
__global__ void k_cvtpad(const float* __restrict__ src, unsigned short* __restrict__ dst,
                         int rows, int ks, int kd){
  int i = blockIdx.x*256 + threadIdx.x;
  if (i >= rows*kd) return;
  int k = i % kd, r = i / kd;
  dst[i] = (k < ks) ? f2bf(src[r*ks + k]) : (unsigned short)0;
}

__global__ void k_bias2(const float* __restrict__ bif, const float* __restrict__ bhf,
                        const float* __restrict__ bib, const float* __restrict__ bhb,
                        float* __restrict__ out){
  int i = blockIdx.x*256 + threadIdx.x;
  if (i >= 8192) return;
  out[i] = (i < 4096) ? (bif[i] + bhf[i]) : (bib[i-4096] + bhb[i-4096]);
}

// ---------------- embedding -> bf16 x[s][b][320] ------------------------------
__global__ void k_embed_bf(const int* __restrict__ que, const float* __restrict__ emb,
                           unsigned short* __restrict__ x){
  int idx = blockIdx.x*256 + threadIdx.x;
  if (idx >= S_*B_*KX) return;
  int e = idx % KX; int sb = idx / KX; int b = sb % B_; int s = sb / B_;
  float v = 0.0f;
  if (e < 300){
    int t = que[b*S_ + s];
    if (t != 0) v = emb[t*300 + e];
  }
  x[idx] = f2bf(v);
}

// ---------------- one LSTM step via MFMA --------------------------------------
// grid (128 unit-tiles of 8, 2 dirs) x 256 thr (4 waves).
// Block tile: all 128 batch rows x 32 cols (8 units x 4 gates; col = gate*8+u).
// Wave w owns rows [w*32, w*32+32). K = 320 (x/wih) + 1024 (h/whh).
__launch_bounds__(256)
__global__ void k_step_mfma(const unsigned short* __restrict__ xbf,
                            const unsigned short* __restrict__ wihc,
                            const unsigned short* __restrict__ whhc,
                            const float* __restrict__ bias2,
                            const unsigned short* __restrict__ hin,
                            unsigned short* __restrict__ hout,
                            float* __restrict__ cst, float* __restrict__ Q, int s){
  const int dir = blockIdx.y;
  const int u0  = blockIdx.x * 8;
  const int tid = threadIdx.x;
  const int wave = tid >> 6, lane = tid & 63;
  const int lr = lane & 15, lk = lane >> 4;

  const int xs = dir ? (S_-1-s) : s;
  const unsigned short* xrow = xbf + (size_t)xs * B_ * KX;
  const unsigned short* hrow = hin + (size_t)dir * B_ * H_;

  // column c -> gate = c>>3, unit = u0 + (c&7); weight row = gate*1024 + unit
  const int cA = lr, cB = 16 + lr;
  const int wrA = (cA >> 3)*1024 + u0 + (cA & 7);
  const int wrB = (cB >> 3)*1024 + u0 + (cB & 7);
  const unsigned short* wihA = wihc + ((size_t)dir*4096 + wrA)*KX;
  const unsigned short* wihB = wihc + ((size_t)dir*4096 + wrB)*KX;
  const unsigned short* whhA = whhc + ((size_t)dir*4096 + wrA)*H_;
  const unsigned short* whhB = whhc + ((size_t)dir*4096 + wrB)*H_;

  const int m0 = wave*32 + lr;        // A-frag 0 row
  const int m1 = wave*32 + 16 + lr;   // A-frag 1 row

  f32x4 acc00{0.f,0.f,0.f,0.f}, acc01{0.f,0.f,0.f,0.f};
  f32x4 acc10{0.f,0.f,0.f,0.f}, acc11{0.f,0.f,0.f,0.f};

  #pragma unroll
  for (int k0 = 0; k0 < KX; k0 += 32){
    const int ko = k0 + lk*8;
    short8v a0 = *(const short8v*)(xrow + (size_t)m0*KX + ko);
    short8v a1 = *(const short8v*)(xrow + (size_t)m1*KX + ko);
    short8v b0 = *(const short8v*)(wihA + ko);
    short8v b1 = *(const short8v*)(wihB + ko);
    acc00 = MFMA16(a0, b0, acc00); acc01 = MFMA16(a0, b1, acc01);
    acc10 = MFMA16(a1, b0, acc10); acc11 = MFMA16(a1, b1, acc11);
  }
  #pragma unroll 4
  for (int k0 = 0; k0 < H_; k0 += 32){
    const int ko = k0 + lk*8;
    short8v a0 = *(const short8v*)(hrow + (size_t)m0*H_ + ko);
    short8v a1 = *(const short8v*)(hrow + (size_t)m1*H_ + ko);
    short8v b0 = *(const short8v*)(whhA + ko);
    short8v b1 = *(const short8v*)(whhB + ko);
    acc00 = MFMA16(a0, b0, acc00); acc01 = MFMA16(a0, b1, acc01);
    acc10 = MFMA16(a1, b0, acc10); acc11 = MFMA16(a1, b1, acc11);
  }

  // C/D layout: row = lk*4+j (within 16), col = lr
  __shared__ float sG[128][33];
  #pragma unroll
  for (int j = 0; j < 4; ++j){
    const int rr = lk*4 + j;
    sG[wave*32 + rr][cA]      = acc00[j];
    sG[wave*32 + rr][cB]      = acc01[j];
    sG[wave*32 + 16 + rr][cA] = acc10[j];
    sG[wave*32 + 16 + rr][cB] = acc11[j];
  }
  __syncthreads();

  const float* bb = bias2 + (size_t)dir*4096;
  float* cc = cst + (size_t)dir*B_*H_;
  unsigned short* ho = hout + (size_t)dir*B_*H_;
  #pragma unroll
  for (int t = 0; t < 4; ++t){
    const int idx = tid + t*256;              // 1024 tasks: 128 m x 8 u
    const int m = idx >> 3, u = idx & 7, ug = u0 + u;
    float gi = sG[m][u]      + bb[ug];
    float gf = sG[m][8+u]    + bb[1024+ug];
    float gg = sG[m][16+u]   + bb[2048+ug];
    float go = sG[m][24+u]   + bb[3072+ug];
    float cold = cc[m*H_ + ug];
    float cn = sigm(gf)*cold + sigm(gi)*tanhf(gg);
    float hn = sigm(go)*tanhf(cn);
    cc[m*H_ + ug] = cn;
    ho[m*H_ + ug] = f2bf(hn);
    Q[((size_t)xs*B_ + m)*2048 + dir*1024 + ug] = hn;
  }
}

// ---------------- qenc L2-normalize (in-place) + enc --------------------------
__global__ void k_qnorm(float* __restrict__ Q, float* __restrict__ enc){
  int sb = blockIdx.x;             // s*128+b
  int s = sb >> 7, b = sb & 127;
  float* row = Q + (size_t)sb*2048;
  int tid = threadIdx.x;
  float v[8]; float ss = 0.f;
  #pragma unroll
  for (int i = 0; i < 8; ++i){ v[i] = row[tid*8+i]; ss += v[i]*v[i]; }
  __shared__ float red[256];
  red[tid] = ss; __syncthreads();
  for (int st = 128; st; st >>= 1){
    if (tid < st) red[tid] += red[tid+st];
    __syncthreads();
  }
  float inv = 1.0f / fmaxf(sqrtf(red[0]), 1e-12f);
  #pragma unroll
  for (int i = 0; i < 8; ++i){
    float q = v[i]*inv;
    row[tid*8+i] = q;
    if (s == S_-1) enc[(size_t)b*2048 + tid*8 + i] = q;
  }
}

// ---------------- per-pixel channel sumsq of img (partial over 256 ch) --------
__global__ void k_sqpart(const float* __restrict__ img, float* __restrict__ part){
  int b = blockIdx.x, cq = blockIdx.y;
  int t = threadIdx.x;
  if (t >= P_) return;
  const float* base = img + ((size_t)b*1024 + cq*256)*P_ + t;
  float s = 0.f;
  #pragma unroll 4
  for (int c = 0; c < 256; ++c){ float v = base[c*P_]; s += v*v; }
  part[((size_t)b*4 + cq)*P_ + t] = s;
}

__global__ void k_invnorm(const float* __restrict__ part, float* __restrict__ inv){
  int i = blockIdx.x*256 + threadIdx.x;
  if (i >= B_*P_) return;
  int b = i / P_, p = i % P_;
  float s = part[(b*4+0)*P_+p] + part[(b*4+1)*P_+p]
          + part[(b*4+2)*P_+p] + part[(b*4+3)*P_+p];
  inv[i] = 1.0f / fmaxf(sqrtf(s), 1e-12f);
}

// ---------------- 3x3 conv, pad 1, 14x14, z-split over K ----------------------
// MODE 0: input = img * inv_norm, channels 1024,1025 are coords (CIN=1026)
// MODE 1: input = plain buffer [B][CIN][196]
// grid (2 o-tiles, 128 b, 2 z): z halves K; partial sums to out[z*NE + ...].
template<int CIN, int MODE>
__launch_bounds__(256)
__global__ void k_conv3(const float* __restrict__ in, const float* __restrict__ inv,
                        const float* __restrict__ w, const float* __restrict__ bias,
                        float* __restrict__ out){
  const int o0 = blockIdx.x * 64;
  const int b  = blockIdx.y;
  const int z  = blockIdx.z;
  constexpr int HALF = ((CIN/2 + 7) / 8) * 8;
  const int cbeg = z * HALF;
  const int cend = z == 0 ? HALF : CIN;
  const int tid = threadIdx.x;
  const int olane = tid & 15;
  const int prow  = tid >> 4;       // image row y (0..13 active)

  __shared__ float sIn[8][16][16];  // [c][y+1][x+1], zero-padded halo
  __shared__ float sW[64][73];      // [o_local][c*9+k], pad to 73

  float acc[4][14];
  #pragma unroll
  for (int i = 0; i < 4; ++i){
    float bz = (z == 0) ? bias[o0 + olane*4 + i] : 0.0f;
    #pragma unroll
    for (int xx = 0; xx < 14; ++xx) acc[i][xx] = bz;
  }

  for (int c0 = cbeg; c0 < cend; c0 += 8){
    const int CH = (cend - c0 < 8) ? (cend - c0) : 8;
    __syncthreads();
    for (int i = tid; i < CH*256; i += 256){
      int cc = i >> 8, r = (i >> 4) & 15, xx = i & 15;
      int y = r - 1, xq = xx - 1;
      float v = 0.f;
      if ((unsigned)y < 14u && (unsigned)xq < 14u){
        int p = y*14 + xq, c = c0 + cc;
        if (MODE == 0){
          if (c < 1024)       v = in[((size_t)b*1024 + c)*P_ + p] * inv[b*P_ + p];
          else if (c == 1024) v = c0f(p);
          else                v = c1f(p);
        } else {
          v = in[((size_t)b*CIN + c)*P_ + p];
        }
      }
      sIn[cc][r][xx] = v;
    }
    for (int i = tid; i < 64*CH*9; i += 256){
      int ol = i / (CH*9), rem = i % (CH*9);
      int cc = rem / 9, k = rem % 9;
      sW[ol][cc*9 + k] = w[((size_t)(o0+ol)*CIN + (c0+cc))*9 + k];
    }
    __syncthreads();
    if (prow < 14){
      for (int cc = 0; cc < CH; ++cc){
        float wreg[4][9];
        #pragma unroll
        for (int i = 0; i < 4; ++i)
          #pragma unroll
          for (int k = 0; k < 9; ++k)
            wreg[i][k] = sW[olane*4+i][cc*9+k];
        #pragma unroll
        for (int dy = 0; dy < 3; ++dy){
          float rr[16];
          #pragma unroll
          for (int xx = 0; xx < 16; ++xx) rr[xx] = sIn[cc][prow+dy][xx];
          #pragma unroll
          for (int xx = 0; xx < 14; ++xx)
            #pragma unroll
            for (int i = 0; i < 4; ++i)
              #pragma unroll
              for (int dx = 0; dx < 3; ++dx)
                acc[i][xx] += rr[xx+dx] * wreg[i][dy*3+dx];
        }
      }
    }
  }
  if (prow < 14){
    #pragma unroll
    for (int i = 0; i < 4; ++i){
      int o = o0 + olane*4 + i;
      #pragma unroll
      for (int xx = 0; xx < 14; ++xx)
        out[(size_t)z*NE + ((size_t)b*OC_ + o)*P_ + prow*14 + xx] = acc[i][xx];
    }
  }
}

// ---------------- BN stats over partial-sum slabs -----------------------------
template<bool SUM2>
__global__ void k_bnstats(const float* __restrict__ t, float* __restrict__ stats){
  int o = blockIdx.x;
  int tid = threadIdx.x;
  float s = 0.f, s2 = 0.f;
  for (int i = tid; i < B_*P_; i += 256){
    int b = i / P_, p = i % P_;
    size_t off = ((size_t)b*OC_ + o)*P_ + p;
    float v = t[off];
    if (SUM2) v += t[off + NE];
    s += v; s2 += v*v;
  }
  __shared__ float r1[256], r2[256];
  r1[tid] = s; r2[tid] = s2; __syncthreads();
  for (int st = 128; st; st >>= 1){
    if (tid < st){ r1[tid] += r1[tid+st]; r2[tid] += r2[tid+st]; }
    __syncthreads();
  }
  if (tid == 0){
    float n = (float)(B_*P_);
    float m = r1[0] / n;
    float var = r2[0] / n - m*m;
    stats[o*2]   = m;
    stats[o*2+1] = rsqrtf(var + 1e-5f);
  }
}

// ---------------- BN apply + relu (+ optional residual add) -------------------
template<bool ADD, bool SUM2>
__global__ void k_bnapply(const float* __restrict__ t, const float* __restrict__ stats,
                          const float* __restrict__ g, const float* __restrict__ bb,
                          const float* __restrict__ addsrc, float* __restrict__ out){
  int idx = blockIdx.x*256 + threadIdx.x;
  if (idx >= NE) return;
  int o = (idx / P_) % OC_;
  float m = stats[o*2], is = stats[o*2+1];
  float x = t[idx];
  if (SUM2) x += t[idx + NE];
  float v = g[o]*(x-m)*is + bb[o];
  v = fmaxf(v, 0.f);
  if (ADD) v += addsrc[idx];
  out[idx] = v;
}

// ---------------- 1x1 conv over [v(128) | coord(2)] + bias + relu -------------
__launch_bounds__(256)
__global__ void k_conv1x1(const float* __restrict__ vin, const float* __restrict__ w,
                          const float* __restrict__ bias, float* __restrict__ out){
  const int b  = blockIdx.x;
  const int o0 = blockIdx.y * 64;
  const int tid = threadIdx.x;
  const int olane = tid & 63, pg = tid >> 6;
  const int o = o0 + olane;

  __shared__ float sV[32][196];
  __shared__ float sW[64][33];

  float acc[49];
  #pragma unroll
  for (int p = 0; p < 49; ++p) acc[p] = 0.f;

  for (int ch = 0; ch < 128; ch += 32){
    __syncthreads();
    for (int i = tid; i < 32*196; i += 256){
      int c = i / 196, p = i % 196;
      sV[c][p] = vin[((size_t)b*128 + ch + c)*P_ + p];
    }
    for (int i = tid; i < 64*32; i += 256){
      int ol = i >> 5, c = i & 31;
      sW[ol][c] = w[(size_t)(o0+ol)*130 + ch + c];
    }
    __syncthreads();
    for (int c = 0; c < 32; ++c){
      float wv = sW[olane][c];
      #pragma unroll
      for (int p = 0; p < 49; ++p) acc[p] += sV[c][pg*49 + p] * wv;
    }
  }
  float w0 = w[(size_t)o*130 + 128], w1 = w[(size_t)o*130 + 129], bz = bias[o];
  #pragma unroll
  for (int p = 0; p < 49; ++p){
    int pp = pg*49 + p;
    float v = acc[p] + w0*c0f(pp) + w1*c1f(pp) + bz;
    out[((size_t)b*128 + o)*P_ + pp] = fmaxf(v, 0.f);
  }
}

} // namespace

// ---------------------------------------------------------------------------
extern "C" void kernel_launch(void* const* d_in, const int* in_sizes, int n_in,
                              void* d_out, int out_size, void* d_ws, size_t ws_size,
                              hipStream_t stream){
  (void)in_sizes; (void)n_in; (void)out_size; (void)ws_size;
  const int*   que  = (const int*)  d_in[0];
  const float* img  = (const float*)d_in[1];
  const float* emb  = (const float*)d_in[2];
  const float* wihf = (const float*)d_in[3];
  const float* whhf = (const float*)d_in[4];
  const float* bihf = (const float*)d_in[5];
  const float* bhhf = (const float*)d_in[6];
  const float* wihb = (const float*)d_in[7];
  const float* whhb = (const float*)d_in[8];
  const float* bihb = (const float*)d_in[9];
  const float* bhhb = (const float*)d_in[10];
  const float* convw = (const float*)d_in[11];
  const float* convb = (const float*)d_in[12];
  const float* bng  = (const float*)d_in[13];
  const float* bnb  = (const float*)d_in[14];
  const float* r1c1w = (const float*)d_in[15];
  const float* r1c1b = (const float*)d_in[16];
  const float* r1c2w = (const float*)d_in[17];
  const float* r1c2b = (const float*)d_in[18];
  const float* r1bng = (const float*)d_in[19];
  const float* r1bnb = (const float*)d_in[20];
  const float* r2c1w = (const float*)d_in[21];
  const float* r2c1b = (const float*)d_in[22];
  const float* r2c2w = (const float*)d_in[23];
  const float* r2c2b = (const float*)d_in[24];
  const float* r2bng = (const float*)d_in[25];
  const float* r2bnb = (const float*)d_in[26];

  float* out  = (float*)d_out;
  float* enc  = out;                        // 128*2048
  float* Q    = out + 262144;               // 32*128*2048 (raw h then normalized)
  float* vout = out + 262144 + 8388608;     // 128*128*196

  // ------ workspace layout (f32 units; all chunks multiple of 64) ------------
  float* ws = (float*)d_ws;
  unsigned short* xbf  = (unsigned short*)ws;            // 32*128*320 bf16
  float* p1 = ws + 655360;
  unsigned short* wihc = (unsigned short*)p1;            // 2*4096*320 bf16
  float* p2 = p1 + 1310720;
  unsigned short* whhc = (unsigned short*)p2;            // 2*4096*1024 bf16
  float* p3 = p2 + 4194304;
  float* bias2 = p3;                                     // 2*4096 f32
  float* p4 = p3 + 8192;
  unsigned short* hstate = (unsigned short*)p4;          // 2par*2dir*128*1024 bf16
  float* p5 = p4 + 262144;
  float* cstate = p5;                                    // 2*128*1024 f32
  float* p6 = p5 + 262144;
  float* part = p6;                                      // 128*4*196
  float* invn = p6 + 100352;                             // 128*196
  float* bufA = invn + 25088;                            // NE
  float* bufB = bufA + NE;                               // NE
  float* convOut = bufB + NE;                            // 2*NE (z-split partials)
  float* stats = convOut + 2*(size_t)NE;                 // 256

  // zero h (both parities) + c state: contiguous 2 MB
  hipMemsetAsync(hstate, 0, (size_t)(262144 + 262144)*sizeof(float), stream);

  // ------ weight/bias/x conversion -------------------------------------------
  k_cvtpad<<<5120, 256, 0, stream>>>(wihf, wihc,                     4096, 300, KX);
  k_cvtpad<<<5120, 256, 0, stream>>>(wihb, wihc + (size_t)4096*KX,   4096, 300, KX);
  k_cvtpad<<<16384,256, 0, stream>>>(whhf, whhc,                     4096, 1024, 1024);
  k_cvtpad<<<16384,256, 0, stream>>>(whhb, whhc + (size_t)4096*1024, 4096, 1024, 1024);
  k_bias2<<<32, 256, 0, stream>>>(bihf, bhhf, bihb, bhhb, bias2);
  k_embed_bf<<<5120, 256, 0, stream>>>(que, emb, xbf);

  // ------ bi-LSTM: 32 MFMA steps ---------------------------------------------
  for (int s = 0; s < 32; ++s){
    unsigned short* hin  = hstate + (size_t)(s & 1)*262144;
    unsigned short* hout = hstate + (size_t)((s & 1)^1)*262144;
    k_step_mfma<<<dim3(128,2), 256, 0, stream>>>(xbf, wihc, whhc, bias2,
                                                 hin, hout, cstate, Q, s);
  }
  k_qnorm<<<4096, 256, 0, stream>>>(Q, enc);

  // ------ image branch ---------------------------------------------------------
  k_sqpart<<<dim3(128,4), 256, 0, stream>>>(img, part);
  k_invnorm<<<(25088+255)/256, 256, 0, stream>>>(part, invn);

  // main conv + BN + relu
  k_conv3<1026,0><<<dim3(2,128,2), 256, 0, stream>>>(img, invn, convw, convb, convOut);
  k_bnstats<true><<<128, 256, 0, stream>>>(convOut, stats);
  k_bnapply<false,true><<<(NE+255)/256, 256, 0, stream>>>(convOut, stats, bng, bnb, bufA, bufA);

  // res block 1: bufA(v) -> bufB(v1) -> convOut -> bufA(v2+v1)
  k_conv1x1<<<dim3(128,2), 256, 0, stream>>>(bufA, r1c1w, r1c1b, bufB);
  k_conv3<128,1><<<dim3(2,128,2), 256, 0, stream>>>(bufB, invn, r1c2w, r1c2b, convOut);
  k_bnstats<true><<<128, 256, 0, stream>>>(convOut, stats);
  k_bnapply<true,true><<<(NE+255)/256, 256, 0, stream>>>(convOut, stats, r1bng, r1bnb, bufB, bufA);

  // res block 2: bufA -> bufB(v1) -> convOut -> vout
  k_conv1x1<<<dim3(128,2), 256, 0, stream>>>(bufA, r2c1w, r2c1b, bufB);
  k_conv3<128,1><<<dim3(2,128,2), 256, 0, stream>>>(bufB, invn, r2c2w, r2c2b, convOut);
  k_bnstats<true><<<128, 256, 0, stream>>>(convOut, stats);
  k_bnapply<true,true><<<(NE+255)/256, 256, 0, stream>>>(convOut, stats, r2bng, r2bnb, bufB, vout);
}

// Round 3
// 1920.604 us; speedup vs baseline: 5.1373x; 1.3175x over previous
//
#include <hip/hip_runtime.h>
#include <hip/hip_bf16.h>
#include <math.h>

// ---------------------------------------------------------------------------
// R3: conv3x3 -> bf16 MFMA implicit GEMM (A=weights M=oc, B=input N=pos,
//     9 shifts = linear LDS row offsets, K=channel chunks of 32, z-split K
//     with SUM2 reduce). LSTM k_step2: LDS-dbuf A staging + L2 B-frags.
// ---------------------------------------------------------------------------

namespace {

constexpr int S_ = 32, B_ = 128, H_ = 1024, P_ = 196, OC_ = 128;
constexpr int NE = B_ * OC_ * P_;        // elems of a [B][128][196] slab
constexpr int KX = 320;                  // padded x-K (300 -> 320)

typedef __attribute__((ext_vector_type(8))) short short8v;
typedef __attribute__((ext_vector_type(4))) float f32x4;
#define MFMA16(a, b, c) __builtin_amdgcn_mfma_f32_16x16x32_bf16((a), (b), (c), 0, 0, 0)

__device__ __forceinline__ float sigm(float x){ return 1.0f/(1.0f + expf(-x)); }
__device__ __forceinline__ float c0f(int p){ return ((float)p/14.0f - 7.0f)/7.0f; }
__device__ __forceinline__ float c1f(int p){ return ((float)(p%14) - 7.0f)/7.0f; }
__device__ __forceinline__ unsigned short f2bf(float x){
  __hip_bfloat16 h = __float2bfloat16(x);
  return *reinterpret_cast<unsigned short*>(&h);
}

// ---------------- weight convert f32 -> bf16, K-padded -----------------------
__global__ void k_cvtpad(const float* __restrict__ src, unsigned short* __restrict__ dst,
                         int rows, int ks, int kd){
  int i = blockIdx.x*256 + threadIdx.x;
  if (i >= rows*kd) return;
  int k = i % kd, r = i / kd;
  dst[i] = (k < ks) ? f2bf(src[r*ks + k]) : (unsigned short)0;
}

// conv weights [oc][cin][3][3] f32 -> wT [s][oc][cpad] bf16
__global__ void k_cvt_wT(const float* __restrict__ w, unsigned short* __restrict__ wT,
                         int cin, int cpad){
  int i = blockIdx.x*256 + threadIdx.x;
  if (i >= 9*128*cpad) return;
  int c = i % cpad; int t = i / cpad; int oc = t % 128; int s = t / 128;
  wT[i] = (c < cin) ? f2bf(w[((size_t)oc*cin + c)*9 + s]) : (unsigned short)0;
}

__global__ void k_bias2(const float* __restrict__ bif, const float* __restrict__ bhf,
                        const float* __restrict__ bib, const float* __restrict__ bhb,
                        float* __restrict__ out){
  int i = blockIdx.x*256 + threadIdx.x;
  if (i >= 8192) return;
  out[i] = (i < 4096) ? (bif[i] + bhf[i]) : (bib[i-4096] + bhb[i-4096]);
}

// ---------------- embedding -> bf16 x[s][b][320] ------------------------------
__global__ void k_embed_bf(const int* __restrict__ que, const float* __restrict__ emb,
                           unsigned short* __restrict__ x){
  int idx = blockIdx.x*256 + threadIdx.x;
  if (idx >= S_*B_*KX) return;
  int e = idx % KX; int sb = idx / KX; int b = sb % B_; int s = sb / B_;
  float v = 0.0f;
  if (e < 300){
    int t = que[b*S_ + s];
    if (t != 0) v = emb[t*300 + e];
  }
  x[idx] = f2bf(v);
}

// ---------------- one LSTM step via MFMA (v2) ---------------------------------
// grid (64 unit-tiles of 16, 2 dirs) x 256 thr. Block: M=128 batch x N=64 cols
// (col = gate*16 + unit_local). A (x|h) LDS double-buffered; B from L2.
// Wave: wfM = wave>>1 (M 64), wfN = wave&1 (N 32): rf4 x cf2.
__launch_bounds__(256, 1)
__global__ void k_step2(const unsigned short* __restrict__ xbf,
                        const unsigned short* __restrict__ wihc,
                        const unsigned short* __restrict__ whhc,
                        const float* __restrict__ bias2,
                        const unsigned short* __restrict__ hin,
                        unsigned short* __restrict__ hout,
                        float* __restrict__ cst, float* __restrict__ Q, int s){
  const int dir = blockIdx.y;
  const int u0  = blockIdx.x * 16;
  const int tid = threadIdx.x, wave = tid >> 6, lane = tid & 63;
  const int lr = lane & 15, lk = lane >> 4;
  const int wfM = wave >> 1, wfN = wave & 1;
  const int xs = dir ? (S_-1-s) : s;
  const unsigned short* xrow = xbf + (size_t)xs*B_*KX;
  const unsigned short* hrow = hin + (size_t)dir*B_*H_;

  __shared__ unsigned short tA[2][128][40];
  __shared__ float sG[128][68];

  const unsigned short* wih = wihc + (size_t)dir*4096*KX;
  const unsigned short* whh = whhc + (size_t)dir*4096*H_;
  const int col0 = wfN*32 + lr, col1 = col0 + 16;
  const int wr0 = (col0 >> 4)*1024 + u0 + (col0 & 15);
  const int wr1 = (col1 >> 4)*1024 + u0 + (col1 & 15);
  const unsigned short* bx0 = wih + (size_t)wr0*KX + lk*8;
  const unsigned short* bx1 = wih + (size_t)wr1*KX + lk*8;
  const unsigned short* bh0 = whh + (size_t)wr0*H_ + lk*8;
  const unsigned short* bh1 = whh + (size_t)wr1*H_ + lk*8;

  const int m_st = tid >> 1, g_st = (tid & 1)*2;   // thread stages rows m_st, groups g_st,g_st+1

  // stage chunk 0 (x-part)
  {
    short8v v0 = *(const short8v*)(xrow + (size_t)m_st*KX + g_st*8);
    short8v v1 = *(const short8v*)(xrow + (size_t)m_st*KX + g_st*8 + 8);
    *(short8v*)&tA[0][m_st][g_st*8]     = v0;
    *(short8v*)&tA[0][m_st][g_st*8 + 8] = v1;
  }
  __syncthreads();

  f32x4 acc[4][2];
  #pragma unroll
  for (int i = 0; i < 4; ++i){ acc[i][0] = f32x4{0,0,0,0}; acc[i][1] = f32x4{0,0,0,0}; }

  int cb = 0;
  for (int ch = 0; ch < 42; ++ch){
    // prefetch next A chunk into regs
    short8v nx0, nx1;
    const bool has = (ch + 1) < 42;
    if (has){
      const unsigned short* src; int K, kb;
      int nc = ch + 1;
      if (nc < 10){ src = xrow; K = KX; kb = nc*32; }
      else        { src = hrow; K = H_; kb = (nc-10)*32; }
      nx0 = *(const short8v*)(src + (size_t)m_st*K + kb + g_st*8);
      nx1 = *(const short8v*)(src + (size_t)m_st*K + kb + g_st*8 + 8);
    }
    // B frags from global (L2)
    short8v b0, b1;
    if (ch < 10){
      b0 = *(const short8v*)(bx0 + ch*32);
      b1 = *(const short8v*)(bx1 + ch*32);
    } else {
      b0 = *(const short8v*)(bh0 + (ch-10)*32);
      b1 = *(const short8v*)(bh1 + (ch-10)*32);
    }
    // A frags from LDS
    #pragma unroll
    for (int rf = 0; rf < 4; ++rf){
      short8v a = *(short8v*)&tA[cb][wfM*64 + rf*16 + lr][lk*8];
      acc[rf][0] = MFMA16(a, b0, acc[rf][0]);
      acc[rf][1] = MFMA16(a, b1, acc[rf][1]);
    }
    if (has){
      *(short8v*)&tA[cb^1][m_st][g_st*8]     = nx0;
      *(short8v*)&tA[cb^1][m_st][g_st*8 + 8] = nx1;
    }
    __syncthreads();
    cb ^= 1;
  }

  // recombine: C row = m (lk*4+j), col = n (lr)
  #pragma unroll
  for (int rf = 0; rf < 4; ++rf)
    #pragma unroll
    for (int cf = 0; cf < 2; ++cf)
      #pragma unroll
      for (int j = 0; j < 4; ++j)
        sG[wfM*64 + rf*16 + lk*4 + j][wfN*32 + cf*16 + lr] = acc[rf][cf][j];
  __syncthreads();

  const float* bb = bias2 + (size_t)dir*4096;
  float* cc = cst + (size_t)dir*B_*H_;
  unsigned short* ho = hout + (size_t)dir*B_*H_;
  #pragma unroll
  for (int t = 0; t < 8; ++t){
    const int idx = tid + t*256;            // 2048 tasks: 128 m x 16 u
    const int m = idx >> 4, u = idx & 15, ug = u0 + u;
    float gi = sG[m][u]      + bb[ug];
    float gf = sG[m][16+u]   + bb[1024+ug];
    float gg = sG[m][32+u]   + bb[2048+ug];
    float go = sG[m][48+u]   + bb[3072+ug];
    float cold = cc[m*H_ + ug];
    float cn = sigm(gf)*cold + sigm(gi)*tanhf(gg);
    float hn = sigm(go)*tanhf(cn);
    cc[m*H_ + ug] = cn;
    ho[m*H_ + ug] = f2bf(hn);
    Q[((size_t)xs*B_ + m)*2048 + dir*1024 + ug] = hn;
  }
}

// ---------------- qenc L2-normalize (in-place) + enc --------------------------
__global__ void k_qnorm(float* __restrict__ Q, float* __restrict__ enc){
  int sb = blockIdx.x;
  int s = sb >> 7, b = sb & 127;
  float* row = Q + (size_t)sb*2048;
  int tid = threadIdx.x;
  float v[8]; float ss = 0.f;
  #pragma unroll
  for (int i = 0; i < 8; ++i){ v[i] = row[tid*8+i]; ss += v[i]*v[i]; }
  __shared__ float red[256];
  red[tid] = ss; __syncthreads();
  for (int st = 128; st; st >>= 1){
    if (tid < st) red[tid] += red[tid+st];
    __syncthreads();
  }
  float inv = 1.0f / fmaxf(sqrtf(red[0]), 1e-12f);
  #pragma unroll
  for (int i = 0; i < 8; ++i){
    float q = v[i]*inv;
    row[tid*8+i] = q;
    if (s == S_-1) enc[(size_t)b*2048 + tid*8 + i] = q;
  }
}

// ---------------- per-pixel channel sumsq of img ------------------------------
__global__ void k_sqpart(const float* __restrict__ img, float* __restrict__ part){
  int b = blockIdx.x, cq = blockIdx.y;
  int t = threadIdx.x;
  if (t >= P_) return;
  const float* base = img + ((size_t)b*1024 + cq*256)*P_ + t;
  float s = 0.f;
  #pragma unroll 4
  for (int c = 0; c < 256; ++c){ float v = base[c*P_]; s += v*v; }
  part[((size_t)b*4 + cq)*P_ + t] = s;
}

__global__ void k_invnorm(const float* __restrict__ part, float* __restrict__ inv){
  int i = blockIdx.x*256 + threadIdx.x;
  if (i >= B_*P_) return;
  int b = i / P_, p = i % P_;
  float s = part[(b*4+0)*P_+p] + part[(b*4+1)*P_+p]
          + part[(b*4+2)*P_+p] + part[(b*4+3)*P_+p];
  inv[i] = 1.0f / fmaxf(sqrtf(s), 1e-12f);
}

// ---------------- 3x3 conv via MFMA -------------------------------------------
// grid (128 b, 2 z); block 256 (4 waves). M=128 oc (A=weights), N=256 padded
// 16x16 positions (B=input), K=c chunks of 32 within z-half.
// Shift (dy,dx) = +dy*16+dx on the B row index. Output C[oc][pos] -> slab[z].
// MODE 0: img*invnorm + coord channels (CIN=1026); MODE 1: plain f32 [b][CIN][196].
template<int CIN, int MODE>
__launch_bounds__(256, 1)
__global__ void k_conv3m(const float* __restrict__ in, const float* __restrict__ invn,
                         const unsigned short* __restrict__ wT, const float* __restrict__ bias,
                         float* __restrict__ out){
  constexpr int CPAD = (CIN + 31) & ~31;
  constexpr int T = CPAD / 32;
  const int b = blockIdx.x, z = blockIdx.y;
  const int chBeg = z ? T/2 : 0;
  const int chEnd = z ? T   : T/2;
  const int tid = threadIdx.x, wave = tid >> 6, lane = tid & 63;
  const int lr = lane & 15, lk = lane >> 4;
  const int wfM = wave >> 1, wfN = wave & 1;

  __shared__ unsigned short tile[296][40];   // [pos][c], halo+tail zeroed once
  __shared__ unsigned short sW[3][128][40];  // [dx][oc][c] for current dy
  __shared__ float sInv[200];

  for (int i = tid; i < 296*40; i += 256) (&tile[0][0])[i] = 0;
  if (MODE == 0) for (int i = tid; i < 196; i += 256) sInv[i] = invn[b*196 + i];

  f32x4 acc[4][8];
  #pragma unroll
  for (int i = 0; i < 4; ++i)
    #pragma unroll
    for (int j = 0; j < 8; ++j) acc[i][j] = f32x4{0,0,0,0};

  for (int ch = chBeg; ch < chEnd; ++ch){
    const int c0 = ch*32;
    __syncthreads();               // prior MFMA reads of tile complete
    // stage input 32c x 196p -> tile[pos][c] (interior only)
    for (int i = tid; i < 32*196; i += 256){
      int c = i / 196, p = i - c*196;
      int cg = c0 + c;
      float v;
      if (MODE == 0){
        if (cg < 1024)       v = in[((size_t)b*1024 + cg)*P_ + p] * sInv[p];
        else if (cg == 1024) v = c0f(p);
        else if (cg == 1025) v = c1f(p);
        else                 v = 0.f;
      } else {
        v = (cg < CIN) ? in[((size_t)b*CIN + cg)*P_ + p] : 0.f;
      }
      int pos = (p/14 + 1)*16 + (p % 14) + 1;
      tile[pos][c] = f2bf(v);
    }
    for (int dy = 0; dy < 3; ++dy){
      __syncthreads();             // prior sW reads done (and tile writes visible)
      // stage weights [3dx][128oc][32c] for (dy, chunk)
      for (int i = tid; i < 1536; i += 256){    // 16B units
        int dx = i >> 9, rem = i & 511, oc = rem >> 2, g = rem & 3;
        short8v v = *(const short8v*)(wT + ((size_t)((dy*3+dx)*128 + oc))*CPAD + c0 + g*8);
        *(short8v*)&sW[dx][oc][g*8] = v;
      }
      __syncthreads();
      #pragma unroll
      for (int dx = 0; dx < 3; ++dx){
        const int dlt = dy*16 + dx;
        short8v a[4];
        #pragma unroll
        for (int rf = 0; rf < 4; ++rf)
          a[rf] = *(short8v*)&sW[dx][wfM*64 + rf*16 + lr][lk*8];
        #pragma unroll
        for (int cf = 0; cf < 8; ++cf){
          short8v bf = *(short8v*)&tile[wfN*128 + cf*16 + lr + dlt][lk*8];
          #pragma unroll
          for (int rf = 0; rf < 4; ++rf)
            acc[rf][cf] = MFMA16(a[rf], bf, acc[rf][cf]);
        }
      }
    }
  }

  // epilogue: C row = oc (lk*4+j), col = pos (lr)
  #pragma unroll
  for (int rf = 0; rf < 4; ++rf){
    #pragma unroll
    for (int j = 0; j < 4; ++j){
      const int oc = wfM*64 + rf*16 + lk*4 + j;
      const float bz = z ? 0.f : bias[oc];
      #pragma unroll
      for (int cf = 0; cf < 8; ++cf){
        const int pos = wfN*128 + cf*16 + lr;
        const int py = pos >> 4, px = pos & 15;
        if (py < 14 && px < 14)
          out[(size_t)z*NE + ((size_t)b*OC_ + oc)*P_ + py*14 + px] = acc[rf][cf][j] + bz;
      }
    }
  }
}

// ---------------- BN stats over 2 partial slabs -------------------------------
__global__ void k_bnstats(const float* __restrict__ t, float* __restrict__ stats){
  int o = blockIdx.x;
  int tid = threadIdx.x;
  float s = 0.f, s2 = 0.f;
  for (int i = tid; i < B_*P_; i += 256){
    int b = i / P_, p = i - (i/P_)*P_;
    size_t off = ((size_t)b*OC_ + o)*P_ + p;
    float v = t[off] + t[off + NE];
    s += v; s2 += v*v;
  }
  __shared__ float r1[256], r2[256];
  r1[tid] = s; r2[tid] = s2; __syncthreads();
  for (int st = 128; st; st >>= 1){
    if (tid < st){ r1[tid] += r1[tid+st]; r2[tid] += r2[tid+st]; }
    __syncthreads();
  }
  if (tid == 0){
    float n = (float)(B_*P_);
    float m = r1[0] / n;
    float var = r2[0] / n - m*m;
    stats[o*2]   = m;
    stats[o*2+1] = rsqrtf(var + 1e-5f);
  }
}

// ---------------- BN apply + relu (+ optional residual add) -------------------
template<bool ADD>
__global__ void k_bnapply(const float* __restrict__ t, const float* __restrict__ stats,
                          const float* __restrict__ g, const float* __restrict__ bb,
                          const float* __restrict__ addsrc, float* __restrict__ out){
  int idx = blockIdx.x*256 + threadIdx.x;
  if (idx >= NE) return;
  int o = (idx / P_) % OC_;
  float m = stats[o*2], is = stats[o*2+1];
  float x = t[idx] + t[idx + NE];
  float v = g[o]*(x-m)*is + bb[o];
  v = fmaxf(v, 0.f);
  if (ADD) v += addsrc[idx];
  out[idx] = v;
}

// ---------------- 1x1 conv over [v(128) | coord(2)] + bias + relu -------------
__launch_bounds__(256)
__global__ void k_conv1x1(const float* __restrict__ vin, const float* __restrict__ w,
                          const float* __restrict__ bias, float* __restrict__ out){
  const int b  = blockIdx.x;
  const int o0 = blockIdx.y * 64;
  const int tid = threadIdx.x;
  const int olane = tid & 63, pg = tid >> 6;
  const int o = o0 + olane;

  __shared__ float sV[32][196];
  __shared__ float sW[64][33];

  float acc[49];
  #pragma unroll
  for (int p = 0; p < 49; ++p) acc[p] = 0.f;

  for (int ch = 0; ch < 128; ch += 32){
    __syncthreads();
    for (int i = tid; i < 32*196; i += 256){
      int c = i / 196, p = i - c*196;
      sV[c][p] = vin[((size_t)b*128 + ch + c)*P_ + p];
    }
    for (int i = tid; i < 64*32; i += 256){
      int ol = i >> 5, c = i & 31;
      sW[ol][c] = w[(size_t)(o0+ol)*130 + ch + c];
    }
    __syncthreads();
    for (int c = 0; c < 32; ++c){
      float wv = sW[olane][c];
      #pragma unroll
      for (int p = 0; p < 49; ++p) acc[p] += sV[c][pg*49 + p] * wv;
    }
  }
  float w0 = w[(size_t)o*130 + 128], w1 = w[(size_t)o*130 + 129], bz = bias[o];
  #pragma unroll
  for (int p = 0; p < 49; ++p){
    int pp = pg*49 + p;
    float v = acc[p] + w0*c0f(pp) + w1*c1f(pp) + bz;
    out[((size_t)b*128 + o)*P_ + pp] = fmaxf(v, 0.f);
  }
}

} // namespace

// ---------------------------------------------------------------------------
extern "C" void kernel_launch(void* const* d_in, const int* in_sizes, int n_in,
                              void* d_out, int out_size, void* d_ws, size_t ws_size,
                              hipStream_t stream){
  (void)in_sizes; (void)n_in; (void)out_size; (void)ws_size;
  const int*   que  = (const int*)  d_in[0];
  const float* img  = (const float*)d_in[1];
  const float* emb  = (const float*)d_in[2];
  const float* wihf = (const float*)d_in[3];
  const float* whhf = (const float*)d_in[4];
  const float* bihf = (const float*)d_in[5];
  const float* bhhf = (const float*)d_in[6];
  const float* wihb = (const float*)d_in[7];
  const float* whhb = (const float*)d_in[8];
  const float* bihb = (const float*)d_in[9];
  const float* bhhb = (const float*)d_in[10];
  const float* convw = (const float*)d_in[11];
  const float* convb = (const float*)d_in[12];
  const float* bng  = (const float*)d_in[13];
  const float* bnb  = (const float*)d_in[14];
  const float* r1c1w = (const float*)d_in[15];
  const float* r1c1b = (const float*)d_in[16];
  const float* r1c2w = (const float*)d_in[17];
  const float* r1c2b = (const float*)d_in[18];
  const float* r1bng = (const float*)d_in[19];
  const float* r1bnb = (const float*)d_in[20];
  const float* r2c1w = (const float*)d_in[21];
  const float* r2c1b = (const float*)d_in[22];
  const float* r2c2w = (const float*)d_in[23];
  const float* r2c2b = (const float*)d_in[24];
  const float* r2bng = (const float*)d_in[25];
  const float* r2bnb = (const float*)d_in[26];

  float* out  = (float*)d_out;
  float* enc  = out;                        // 128*2048
  float* Q    = out + 262144;               // 32*128*2048
  float* vout = out + 262144 + 8388608;     // 128*128*196

  // ------ workspace layout (f32 units; chunks multiple of 64) -----------------
  float* ws = (float*)d_ws;
  unsigned short* xbf  = (unsigned short*)ws;            // 32*128*320 bf16
  float* p1 = ws + 655360;
  unsigned short* wihc = (unsigned short*)p1;            // 2*4096*320 bf16
  float* p2 = p1 + 1310720;
  unsigned short* whhc = (unsigned short*)p2;            // 2*4096*1024 bf16
  float* p3 = p2 + 4194304;
  float* bias2 = p3;                                     // 2*4096
  float* p4 = p3 + 8192;
  unsigned short* hstate = (unsigned short*)p4;          // 2par*2dir*128*1024 bf16
  float* p5 = p4 + 262144;
  float* cstate = p5;                                    // 2*128*1024
  float* p6 = p5 + 262144;
  float* part = p6;                                      // 128*4*196
  float* invn = p6 + 100352;                             // 128*196
  float* bufA = invn + 25088;                            // NE
  float* bufB = bufA + NE;                               // NE
  float* convOut = bufB + NE;                            // 2*NE partial slabs
  float* p7 = convOut + 2*(size_t)NE;
  float* stats = p7;                                     // 256
  float* p8 = p7 + 256;
  unsigned short* wTc  = (unsigned short*)p8;            // 9*128*1056 bf16
  float* p9 = p8 + 608256;
  unsigned short* wTr1 = (unsigned short*)p9;            // 9*128*128 bf16
  float* p10 = p9 + 73728;
  unsigned short* wTr2 = (unsigned short*)p10;           // 9*128*128 bf16

  hipMemsetAsync(hstate, 0, (size_t)(262144 + 262144)*sizeof(float), stream);

  // ------ conversions ---------------------------------------------------------
  k_cvtpad<<<5120, 256, 0, stream>>>(wihf, wihc,                     4096, 300, KX);
  k_cvtpad<<<5120, 256, 0, stream>>>(wihb, wihc + (size_t)4096*KX,   4096, 300, KX);
  k_cvtpad<<<16384,256, 0, stream>>>(whhf, whhc,                     4096, 1024, 1024);
  k_cvtpad<<<16384,256, 0, stream>>>(whhb, whhc + (size_t)4096*1024, 4096, 1024, 1024);
  k_bias2<<<32, 256, 0, stream>>>(bihf, bhhf, bihb, bhhb, bias2);
  k_embed_bf<<<5120, 256, 0, stream>>>(que, emb, xbf);
  k_cvt_wT<<<(9*128*1056 + 255)/256, 256, 0, stream>>>(convw, wTc, 1026, 1056);
  k_cvt_wT<<<(9*128*128 + 255)/256, 256, 0, stream>>>(r1c2w, wTr1, 128, 128);
  k_cvt_wT<<<(9*128*128 + 255)/256, 256, 0, stream>>>(r2c2w, wTr2, 128, 128);

  // ------ bi-LSTM -------------------------------------------------------------
  for (int s = 0; s < 32; ++s){
    unsigned short* hin  = hstate + (size_t)(s & 1)*262144;
    unsigned short* hout = hstate + (size_t)((s & 1)^1)*262144;
    k_step2<<<dim3(64,2), 256, 0, stream>>>(xbf, wihc, whhc, bias2,
                                            hin, hout, cstate, Q, s);
  }
  k_qnorm<<<4096, 256, 0, stream>>>(Q, enc);

  // ------ image branch --------------------------------------------------------
  k_sqpart<<<dim3(128,4), 256, 0, stream>>>(img, part);
  k_invnorm<<<(25088+255)/256, 256, 0, stream>>>(part, invn);

  k_conv3m<1026,0><<<dim3(128,2), 256, 0, stream>>>(img, invn, wTc, convb, convOut);
  k_bnstats<<<128, 256, 0, stream>>>(convOut, stats);
  k_bnapply<false><<<(NE+255)/256, 256, 0, stream>>>(convOut, stats, bng, bnb, bufA, bufA);

  // res block 1: bufA(v) -> bufB(v1) -> convOut -> bufA(v2+v1)
  k_conv1x1<<<dim3(128,2), 256, 0, stream>>>(bufA, r1c1w, r1c1b, bufB);
  k_conv3m<128,1><<<dim3(128,2), 256, 0, stream>>>(bufB, invn, wTr1, r1c2b, convOut);
  k_bnstats<<<128, 256, 0, stream>>>(convOut, stats);
  k_bnapply<true><<<(NE+255)/256, 256, 0, stream>>>(convOut, stats, r1bng, r1bnb, bufB, bufA);

  // res block 2: bufA -> bufB(v1) -> convOut -> vout
  k_conv1x1<<<dim3(128,2), 256, 0, stream>>>(bufA, r2c1w, r2c1b, bufB);
  k_conv3m<128,1><<<dim3(128,2), 256, 0, stream>>>(bufB, invn, wTr2, r2c2b, convOut);
  k_bnstats<<<128, 256, 0, stream>>>(convOut, stats);
  k_bnapply<true><<<(NE+255)/256, 256, 0, stream>>>(convOut, stats, r2bng, r2bnb, bufB, vout);
}

// Round 4
// 1406.040 us; speedup vs baseline: 7.0174x; 1.3660x over previous
//
#include <hip/hip_runtime.h>
#include <hip/hip_bf16.h>
#include <math.h>

// ---------------------------------------------------------------------------
// R4: conv3m v2 — weights A-frags direct from L2 (no sW LDS), input tile
//     double-buffered, 1 barrier/chunk. LSTM k_step3 — 256 blocks, A+B LDS
//     double-buffer with register prefetch, 1 barrier/chunk.
// ---------------------------------------------------------------------------

namespace {

constexpr int S_ = 32, B_ = 128, H_ = 1024, P_ = 196, OC_ = 128;
constexpr int NE = B_ * OC_ * P_;        // elems of a [B][128][196] slab
constexpr int KX = 320;                  // padded x-K (300 -> 320)

typedef __attribute__((ext_vector_type(8))) short short8v;
typedef __attribute__((ext_vector_type(4))) float f32x4;
#define MFMA16(a, b, c) __builtin_amdgcn_mfma_f32_16x16x32_bf16((a), (b), (c), 0, 0, 0)

__device__ __forceinline__ float sigm(float x){ return 1.0f/(1.0f + expf(-x)); }
__device__ __forceinline__ float c0f(int p){ return ((float)p/14.0f - 7.0f)/7.0f; }
__device__ __forceinline__ float c1f(int p){ return ((float)(p%14) - 7.0f)/7.0f; }
__device__ __forceinline__ unsigned short f2bf(float x){
  __hip_bfloat16 h = __float2bfloat16(x);
  return *reinterpret_cast<unsigned short*>(&h);
}

// ---------------- weight convert f32 -> bf16, K-padded -----------------------
__global__ void k_cvtpad(const float* __restrict__ src, unsigned short* __restrict__ dst,
                         int rows, int ks, int kd){
  int i = blockIdx.x*256 + threadIdx.x;
  if (i >= rows*kd) return;
  int k = i % kd, r = i / kd;
  dst[i] = (k < ks) ? f2bf(src[r*ks + k]) : (unsigned short)0;
}

// conv weights [oc][cin][3][3] f32 -> wT [s][oc][cpad] bf16
__global__ void k_cvt_wT(const float* __restrict__ w, unsigned short* __restrict__ wT,
                         int cin, int cpad){
  int i = blockIdx.x*256 + threadIdx.x;
  if (i >= 9*128*cpad) return;
  int c = i % cpad; int t = i / cpad; int oc = t % 128; int s = t / 128;
  wT[i] = (c < cin) ? f2bf(w[((size_t)oc*cin + c)*9 + s]) : (unsigned short)0;
}

__global__ void k_bias2(const float* __restrict__ bif, const float* __restrict__ bhf,
                        const float* __restrict__ bib, const float* __restrict__ bhb,
                        float* __restrict__ out){
  int i = blockIdx.x*256 + threadIdx.x;
  if (i >= 8192) return;
  out[i] = (i < 4096) ? (bif[i] + bhf[i]) : (bib[i-4096] + bhb[i-4096]);
}

// ---------------- embedding -> bf16 x[s][b][320] ------------------------------
__global__ void k_embed_bf(const int* __restrict__ que, const float* __restrict__ emb,
                           unsigned short* __restrict__ x){
  int idx = blockIdx.x*256 + threadIdx.x;
  if (idx >= S_*B_*KX) return;
  int e = idx % KX; int sb = idx / KX; int b = sb % B_; int s = sb / B_;
  float v = 0.0f;
  if (e < 300){
    int t = que[b*S_ + s];
    if (t != 0) v = emb[t*300 + e];
  }
  x[idx] = f2bf(v);
}

// ---------------- one LSTM step via MFMA (v3) ---------------------------------
// grid (128 unit-tiles of 8, 2 dirs) x 256 thr (4 waves).
// Block tile: M=128 batch x N=32 cols (col = gate*8 + u). Wave w: rows 32w..+32.
// A (x|h) and B (weights) double-buffered in LDS; register prefetch; one
// barrier per K-chunk of 32. K = 10 x-chunks + 32 h-chunks = 42.
__launch_bounds__(256, 1)
__global__ void k_step3(const unsigned short* __restrict__ xbf,
                        const unsigned short* __restrict__ wihc,
                        const unsigned short* __restrict__ whhc,
                        const float* __restrict__ bias2,
                        const unsigned short* __restrict__ hin,
                        unsigned short* __restrict__ hout,
                        float* __restrict__ cst, float* __restrict__ Q, int s){
  const int dir = blockIdx.y;
  const int u0  = blockIdx.x * 8;
  const int tid = threadIdx.x, wave = tid >> 6, lane = tid & 63;
  const int lr = lane & 15, lk = lane >> 4;
  const int xs = dir ? (S_-1-s) : s;
  const unsigned short* xrow = xbf + (size_t)xs*B_*KX;
  const unsigned short* hrow = hin + (size_t)dir*B_*H_;
  const unsigned short* wih = wihc + (size_t)dir*4096*KX;
  const unsigned short* whh = whhc + (size_t)dir*4096*H_;

  __shared__ unsigned short tA[2][128][40];
  __shared__ unsigned short tB[2][32][40];
  __shared__ float sG[128][33];

  // staging assignment: A: thread stages row mA, 16 shorts at col hA*16.
  const int mA = tid >> 1, hA = tid & 1;
  // B: threads 0..127 stage col colS, 8 shorts at (tid&3)*8.
  const int colS = tid >> 2, kqS = (tid & 3)*8;
  const int wrS = (colS >> 3)*1024 + u0 + (colS & 7);

  // chunk 0 (x-part) straight to LDS
  {
    *(short8v*)&tA[0][mA][hA*16]     = *(const short8v*)(xrow + (size_t)mA*KX + hA*16);
    *(short8v*)&tA[0][mA][hA*16 + 8] = *(const short8v*)(xrow + (size_t)mA*KX + hA*16 + 8);
    if (tid < 128)
      *(short8v*)&tB[0][colS][kqS] = *(const short8v*)(wih + (size_t)wrS*KX + kqS);
  }
  __syncthreads();

  f32x4 acc00{0,0,0,0}, acc01{0,0,0,0}, acc10{0,0,0,0}, acc11{0,0,0,0};
  const int m0 = wave*32 + lr, m1 = wave*32 + 16 + lr;

  for (int ch = 0; ch < 42; ++ch){
    const int cb = ch & 1;
    // prefetch next chunk into regs (issue-early)
    short8v pa0, pa1, pb;
    const bool has = (ch + 1) < 42;
    if (has){
      const int nc = ch + 1;
      const unsigned short* s_; int K_, kb_;
      if (nc < 10){ s_ = xrow; K_ = KX; kb_ = nc*32; }
      else        { s_ = hrow; K_ = H_; kb_ = (nc-10)*32; }
      pa0 = *(const short8v*)(s_ + (size_t)mA*K_ + kb_ + hA*16);
      pa1 = *(const short8v*)(s_ + (size_t)mA*K_ + kb_ + hA*16 + 8);
      if (tid < 128){
        const unsigned short* wb = (nc < 10) ? (wih + (size_t)wrS*KX) : (whh + (size_t)wrS*H_);
        pb = *(const short8v*)(wb + kb_ + kqS);
      }
    }
    // MFMA on current chunk
    short8v a0 = *(short8v*)&tA[cb][m0][lk*8];
    short8v a1 = *(short8v*)&tA[cb][m1][lk*8];
    short8v b0 = *(short8v*)&tB[cb][lr][lk*8];
    short8v b1 = *(short8v*)&tB[cb][16 + lr][lk*8];
    acc00 = MFMA16(a0, b0, acc00); acc01 = MFMA16(a0, b1, acc01);
    acc10 = MFMA16(a1, b0, acc10); acc11 = MFMA16(a1, b1, acc11);
    // write-late
    if (has){
      *(short8v*)&tA[cb^1][mA][hA*16]     = pa0;
      *(short8v*)&tA[cb^1][mA][hA*16 + 8] = pa1;
      if (tid < 128) *(short8v*)&tB[cb^1][colS][kqS] = pb;
    }
    __syncthreads();
  }

  // C/D: row = lk*4+j, col = lr
  #pragma unroll
  for (int j = 0; j < 4; ++j){
    const int rr = lk*4 + j;
    sG[wave*32 + rr][lr]           = acc00[j];
    sG[wave*32 + rr][16 + lr]      = acc01[j];
    sG[wave*32 + 16 + rr][lr]      = acc10[j];
    sG[wave*32 + 16 + rr][16 + lr] = acc11[j];
  }
  __syncthreads();

  const float* bb = bias2 + (size_t)dir*4096;
  float* cc = cst + (size_t)dir*B_*H_;
  unsigned short* ho = hout + (size_t)dir*B_*H_;
  #pragma unroll
  for (int t = 0; t < 4; ++t){
    const int idx = tid + t*256;              // 1024 tasks: 128 m x 8 u
    const int m = idx >> 3, u = idx & 7, ug = u0 + u;
    float gi = sG[m][u]      + bb[ug];
    float gf = sG[m][8+u]    + bb[1024+ug];
    float gg = sG[m][16+u]   + bb[2048+ug];
    float go = sG[m][24+u]   + bb[3072+ug];
    float cold = cc[m*H_ + ug];
    float cn = sigm(gf)*cold + sigm(gi)*tanhf(gg);
    float hn = sigm(go)*tanhf(cn);
    cc[m*H_ + ug] = cn;
    ho[m*H_ + ug] = f2bf(hn);
    Q[((size_t)xs*B_ + m)*2048 + dir*1024 + ug] = hn;
  }
}

// ---------------- qenc L2-normalize (in-place) + enc --------------------------
__global__ void k_qnorm(float* __restrict__ Q, float* __restrict__ enc){
  int sb = blockIdx.x;
  int s = sb >> 7, b = sb & 127;
  float* row = Q + (size_t)sb*2048;
  int tid = threadIdx.x;
  float v[8]; float ss = 0.f;
  #pragma unroll
  for (int i = 0; i < 8; ++i){ v[i] = row[tid*8+i]; ss += v[i]*v[i]; }
  __shared__ float red[256];
  red[tid] = ss; __syncthreads();
  for (int st = 128; st; st >>= 1){
    if (tid < st) red[tid] += red[tid+st];
    __syncthreads();
  }
  float inv = 1.0f / fmaxf(sqrtf(red[0]), 1e-12f);
  #pragma unroll
  for (int i = 0; i < 8; ++i){
    float q = v[i]*inv;
    row[tid*8+i] = q;
    if (s == S_-1) enc[(size_t)b*2048 + tid*8 + i] = q;
  }
}

// ---------------- per-pixel channel sumsq of img ------------------------------
__global__ void k_sqpart(const float* __restrict__ img, float* __restrict__ part){
  int b = blockIdx.x, cq = blockIdx.y;
  int t = threadIdx.x;
  if (t >= P_) return;
  const float* base = img + ((size_t)b*1024 + cq*256)*P_ + t;
  float s = 0.f;
  #pragma unroll 4
  for (int c = 0; c < 256; ++c){ float v = base[c*P_]; s += v*v; }
  part[((size_t)b*4 + cq)*P_ + t] = s;
}

__global__ void k_invnorm(const float* __restrict__ part, float* __restrict__ inv){
  int i = blockIdx.x*256 + threadIdx.x;
  if (i >= B_*P_) return;
  int b = i / P_, p = i % P_;
  float s = part[(b*4+0)*P_+p] + part[(b*4+1)*P_+p]
          + part[(b*4+2)*P_+p] + part[(b*4+3)*P_+p];
  inv[i] = 1.0f / fmaxf(sqrtf(s), 1e-12f);
}

// ---------------- 3x3 conv via MFMA (v2) ---------------------------------------
// grid (128 b, 2 z); block 256 (4 waves). M=128 oc (A=weights from L2),
// N=256 padded 16x16 positions (B=input tile, LDS dbuf), K chunks of 32.
// One barrier per chunk; stage of next chunk issued after the dy=0 group.
template<int CIN, int MODE>
__device__ __forceinline__ void conv_stage(unsigned short (*__restrict__ tile)[40],
                                           const float* __restrict__ in,
                                           const float* __restrict__ sInv,
                                           int b, int c0, int tid){
  for (int i = tid; i < 32*196; i += 256){
    int c = i / 196, p = i - c*196;
    int cg = c0 + c;
    float v;
    if (MODE == 0){
      if (cg < 1024)       v = in[((size_t)b*1024 + cg)*P_ + p] * sInv[p];
      else if (cg == 1024) v = c0f(p);
      else if (cg == 1025) v = c1f(p);
      else                 v = 0.f;
    } else {
      v = in[((size_t)b*CIN + cg)*P_ + p];
    }
    int py = p / 14;
    int pos = (py + 1)*16 + (p - py*14) + 1;
    tile[pos][c] = f2bf(v);
  }
}

template<int CIN, int MODE>
__launch_bounds__(256, 1)
__global__ void k_conv3m(const float* __restrict__ in, const float* __restrict__ invn,
                         const unsigned short* __restrict__ wT, const float* __restrict__ bias,
                         float* __restrict__ out){
  constexpr int CPAD = (CIN + 31) & ~31;
  constexpr int T = CPAD / 32;
  const int b = blockIdx.x, z = blockIdx.y;
  const int chBeg = (z*T)/2, chEnd = ((z+1)*T)/2;
  const int tid = threadIdx.x, wave = tid >> 6, lane = tid & 63;
  const int lr = lane & 15, lk = lane >> 4;
  const int wfM = wave >> 1, wfN = wave & 1;

  __shared__ unsigned short tile[2][296][40];
  __shared__ float sInv[200];

  for (int i = tid; i < 2*296*40; i += 256) (&tile[0][0][0])[i] = 0;
  if (MODE == 0) for (int i = tid; i < 196; i += 256) sInv[i] = invn[b*196 + i];
  __syncthreads();
  conv_stage<CIN,MODE>(tile[0], in, sInv, b, chBeg*32, tid);
  __syncthreads();

  f32x4 acc[4][8];
  #pragma unroll
  for (int i = 0; i < 4; ++i)
    #pragma unroll
    for (int j = 0; j < 8; ++j) acc[i][j] = f32x4{0,0,0,0};

  for (int ch = chBeg; ch < chEnd; ++ch){
    const int cur = (ch - chBeg) & 1;
    #pragma unroll
    for (int dy = 0; dy < 3; ++dy){
      #pragma unroll
      for (int dx = 0; dx < 3; ++dx){
        const int dlt = dy*16 + dx;
        short8v a[4];
        #pragma unroll
        for (int rf = 0; rf < 4; ++rf)
          a[rf] = *(const short8v*)(wT + ((size_t)((dy*3+dx)*128) + wfM*64 + rf*16 + lr)*CPAD
                                       + ch*32 + lk*8);
        #pragma unroll
        for (int cf = 0; cf < 8; ++cf){
          short8v bf = *(short8v*)&tile[cur][wfN*128 + cf*16 + lr + dlt][lk*8];
          #pragma unroll
          for (int rf = 0; rf < 4; ++rf)
            acc[rf][cf] = MFMA16(a[rf], bf, acc[rf][cf]);
        }
      }
      // hide next-chunk staging under dy=1,2 MFMA groups
      if (dy == 0 && ch + 1 < chEnd)
        conv_stage<CIN,MODE>(tile[cur^1], in, sInv, b, (ch+1)*32, tid);
    }
    __syncthreads();
  }

  // epilogue: C row = oc (lk*4+j), col = pos (lr)
  #pragma unroll
  for (int rf = 0; rf < 4; ++rf){
    #pragma unroll
    for (int j = 0; j < 4; ++j){
      const int oc = wfM*64 + rf*16 + lk*4 + j;
      const float bz = z ? 0.f : bias[oc];
      #pragma unroll
      for (int cf = 0; cf < 8; ++cf){
        const int pos = wfN*128 + cf*16 + lr;
        const int py = pos >> 4, px = pos & 15;
        if (py < 14 && px < 14)
          out[(size_t)z*NE + ((size_t)b*OC_ + oc)*P_ + py*14 + px] = acc[rf][cf][j] + bz;
      }
    }
  }
}

// ---------------- BN stats over 2 partial slabs -------------------------------
__global__ void k_bnstats(const float* __restrict__ t, float* __restrict__ stats){
  int o = blockIdx.x;
  int tid = threadIdx.x;
  float s = 0.f, s2 = 0.f;
  for (int i = tid; i < B_*P_; i += 256){
    int b = i / P_, p = i - (i/P_)*P_;
    size_t off = ((size_t)b*OC_ + o)*P_ + p;
    float v = t[off] + t[off + NE];
    s += v; s2 += v*v;
  }
  __shared__ float r1[256], r2[256];
  r1[tid] = s; r2[tid] = s2; __syncthreads();
  for (int st = 128; st; st >>= 1){
    if (tid < st){ r1[tid] += r1[tid+st]; r2[tid] += r2[tid+st]; }
    __syncthreads();
  }
  if (tid == 0){
    float n = (float)(B_*P_);
    float m = r1[0] / n;
    float var = r2[0] / n - m*m;
    stats[o*2]   = m;
    stats[o*2+1] = rsqrtf(var + 1e-5f);
  }
}

// ---------------- BN apply + relu (+ optional residual add) -------------------
template<bool ADD>
__global__ void k_bnapply(const float* __restrict__ t, const float* __restrict__ stats,
                          const float* __restrict__ g, const float* __restrict__ bb,
                          const float* __restrict__ addsrc, float* __restrict__ out){
  int idx = blockIdx.x*256 + threadIdx.x;
  if (idx >= NE) return;
  int o = (idx / P_) % OC_;
  float m = stats[o*2], is = stats[o*2+1];
  float x = t[idx] + t[idx + NE];
  float v = g[o]*(x-m)*is + bb[o];
  v = fmaxf(v, 0.f);
  if (ADD) v += addsrc[idx];
  out[idx] = v;
}

// ---------------- 1x1 conv over [v(128) | coord(2)] + bias + relu -------------
__launch_bounds__(256)
__global__ void k_conv1x1(const float* __restrict__ vin, const float* __restrict__ w,
                          const float* __restrict__ bias, float* __restrict__ out){
  const int b  = blockIdx.x;
  const int o0 = blockIdx.y * 64;
  const int tid = threadIdx.x;
  const int olane = tid & 63, pg = tid >> 6;
  const int o = o0 + olane;

  __shared__ float sV[32][196];
  __shared__ float sW[64][33];

  float acc[49];
  #pragma unroll
  for (int p = 0; p < 49; ++p) acc[p] = 0.f;

  for (int ch = 0; ch < 128; ch += 32){
    __syncthreads();
    for (int i = tid; i < 32*196; i += 256){
      int c = i / 196, p = i - c*196;
      sV[c][p] = vin[((size_t)b*128 + ch + c)*P_ + p];
    }
    for (int i = tid; i < 64*32; i += 256){
      int ol = i >> 5, c = i & 31;
      sW[ol][c] = w[(size_t)(o0+ol)*130 + ch + c];
    }
    __syncthreads();
    for (int c = 0; c < 32; ++c){
      float wv = sW[olane][c];
      #pragma unroll
      for (int p = 0; p < 49; ++p) acc[p] += sV[c][pg*49 + p] * wv;
    }
  }
  float w0 = w[(size_t)o*130 + 128], w1 = w[(size_t)o*130 + 129], bz = bias[o];
  #pragma unroll
  for (int p = 0; p < 49; ++p){
    int pp = pg*49 + p;
    float v = acc[p] + w0*c0f(pp) + w1*c1f(pp) + bz;
    out[((size_t)b*128 + o)*P_ + pp] = fmaxf(v, 0.f);
  }
}

} // namespace

// ---------------------------------------------------------------------------
extern "C" void kernel_launch(void* const* d_in, const int* in_sizes, int n_in,
                              void* d_out, int out_size, void* d_ws, size_t ws_size,
                              hipStream_t stream){
  (void)in_sizes; (void)n_in; (void)out_size; (void)ws_size;
  const int*   que  = (const int*)  d_in[0];
  const float* img  = (const float*)d_in[1];
  const float* emb  = (const float*)d_in[2];
  const float* wihf = (const float*)d_in[3];
  const float* whhf = (const float*)d_in[4];
  const float* bihf = (const float*)d_in[5];
  const float* bhhf = (const float*)d_in[6];
  const float* wihb = (const float*)d_in[7];
  const float* whhb = (const float*)d_in[8];
  const float* bihb = (const float*)d_in[9];
  const float* bhhb = (const float*)d_in[10];
  const float* convw = (const float*)d_in[11];
  const float* convb = (const float*)d_in[12];
  const float* bng  = (const float*)d_in[13];
  const float* bnb  = (const float*)d_in[14];
  const float* r1c1w = (const float*)d_in[15];
  const float* r1c1b = (const float*)d_in[16];
  const float* r1c2w = (const float*)d_in[17];
  const float* r1c2b = (const float*)d_in[18];
  const float* r1bng = (const float*)d_in[19];
  const float* r1bnb = (const float*)d_in[20];
  const float* r2c1w = (const float*)d_in[21];
  const float* r2c1b = (const float*)d_in[22];
  const float* r2c2w = (const float*)d_in[23];
  const float* r2c2b = (const float*)d_in[24];
  const float* r2bng = (const float*)d_in[25];
  const float* r2bnb = (const float*)d_in[26];

  float* out  = (float*)d_out;
  float* enc  = out;                        // 128*2048
  float* Q    = out + 262144;               // 32*128*2048
  float* vout = out + 262144 + 8388608;     // 128*128*196

  // ------ workspace layout (f32 units) ----------------------------------------
  float* ws = (float*)d_ws;
  unsigned short* xbf  = (unsigned short*)ws;            // 32*128*320 bf16
  float* p1 = ws + 655360;
  unsigned short* wihc = (unsigned short*)p1;            // 2*4096*320 bf16
  float* p2 = p1 + 1310720;
  unsigned short* whhc = (unsigned short*)p2;            // 2*4096*1024 bf16
  float* p3 = p2 + 4194304;
  float* bias2 = p3;                                     // 2*4096
  float* p4 = p3 + 8192;
  unsigned short* hstate = (unsigned short*)p4;          // 2par*2dir*128*1024 bf16
  float* p5 = p4 + 262144;
  float* cstate = p5;                                    // 2*128*1024
  float* p6 = p5 + 262144;
  float* part = p6;                                      // 128*4*196
  float* invn = p6 + 100352;                             // 128*196
  float* bufA = invn + 25088;                            // NE
  float* bufB = bufA + NE;                               // NE
  float* convOut = bufB + NE;                            // 2*NE partial slabs
  float* p7 = convOut + 2*(size_t)NE;
  float* stats = p7;                                     // 256
  float* p8 = p7 + 256;
  unsigned short* wTc  = (unsigned short*)p8;            // 9*128*1056 bf16
  float* p9 = p8 + 608256;
  unsigned short* wTr1 = (unsigned short*)p9;            // 9*128*128 bf16
  float* p10 = p9 + 73728;
  unsigned short* wTr2 = (unsigned short*)p10;           // 9*128*128 bf16

  hipMemsetAsync(hstate, 0, (size_t)(262144 + 262144)*sizeof(float), stream);

  // ------ conversions ---------------------------------------------------------
  k_cvtpad<<<5120, 256, 0, stream>>>(wihf, wihc,                     4096, 300, KX);
  k_cvtpad<<<5120, 256, 0, stream>>>(wihb, wihc + (size_t)4096*KX,   4096, 300, KX);
  k_cvtpad<<<16384,256, 0, stream>>>(whhf, whhc,                     4096, 1024, 1024);
  k_cvtpad<<<16384,256, 0, stream>>>(whhb, whhc + (size_t)4096*1024, 4096, 1024, 1024);
  k_bias2<<<32, 256, 0, stream>>>(bihf, bhhf, bihb, bhhb, bias2);
  k_embed_bf<<<5120, 256, 0, stream>>>(que, emb, xbf);
  k_cvt_wT<<<(9*128*1056 + 255)/256, 256, 0, stream>>>(convw, wTc, 1026, 1056);
  k_cvt_wT<<<(9*128*128 + 255)/256, 256, 0, stream>>>(r1c2w, wTr1, 128, 128);
  k_cvt_wT<<<(9*128*128 + 255)/256, 256, 0, stream>>>(r2c2w, wTr2, 128, 128);

  // ------ bi-LSTM -------------------------------------------------------------
  for (int s = 0; s < 32; ++s){
    unsigned short* hin  = hstate + (size_t)(s & 1)*262144;
    unsigned short* hout = hstate + (size_t)((s & 1)^1)*262144;
    k_step3<<<dim3(128,2), 256, 0, stream>>>(xbf, wihc, whhc, bias2,
                                             hin, hout, cstate, Q, s);
  }
  k_qnorm<<<4096, 256, 0, stream>>>(Q, enc);

  // ------ image branch --------------------------------------------------------
  k_sqpart<<<dim3(128,4), 256, 0, stream>>>(img, part);
  k_invnorm<<<(25088+255)/256, 256, 0, stream>>>(part, invn);

  k_conv3m<1026,0><<<dim3(128,2), 256, 0, stream>>>(img, invn, wTc, convb, convOut);
  k_bnstats<<<128, 256, 0, stream>>>(convOut, stats);
  k_bnapply<false><<<(NE+255)/256, 256, 0, stream>>>(convOut, stats, bng, bnb, bufA, bufA);

  // res block 1: bufA(v) -> bufB(v1) -> convOut -> bufA(v2+v1)
  k_conv1x1<<<dim3(128,2), 256, 0, stream>>>(bufA, r1c1w, r1c1b, bufB);
  k_conv3m<128,1><<<dim3(128,2), 256, 0, stream>>>(bufB, invn, wTr1, r1c2b, convOut);
  k_bnstats<<<128, 256, 0, stream>>>(convOut, stats);
  k_bnapply<true><<<(NE+255)/256, 256, 0, stream>>>(convOut, stats, r1bng, r1bnb, bufB, bufA);

  // res block 2: bufA -> bufB(v1) -> convOut -> vout
  k_conv1x1<<<dim3(128,2), 256, 0, stream>>>(bufA, r2c1w, r2c1b, bufB);
  k_conv3m<128,1><<<dim3(128,2), 256, 0, stream>>>(bufB, invn, wTr2, r2c2b, convOut);
  k_bnstats<<<128, 256, 0, stream>>>(convOut, stats);
  k_bnapply<true><<<(NE+255)/256, 256, 0, stream>>>(convOut, stats, r2bng, r2bnb, bufB, vout);
}

// Round 5
// 1378.129 us; speedup vs baseline: 7.1595x; 1.0203x over previous
//
#include <hip/hip_runtime.h>
#include <hip/hip_bf16.h>
#include <math.h>

// ---------------------------------------------------------------------------
// R5: kill exposed latency. conv_stage -> 13/12 register-batched loads (MLP).
//     k_step4 -> K-chunk 128 (11 chunks vs 42), x padded to 384.
// ---------------------------------------------------------------------------

namespace {

constexpr int S_ = 32, B_ = 128, H_ = 1024, P_ = 196, OC_ = 128;
constexpr int NE = B_ * OC_ * P_;        // elems of a [B][128][196] slab
constexpr int KX = 384;                  // padded x-K (300 -> 384, 3 chunks of 128)

typedef __attribute__((ext_vector_type(8))) short short8v;
typedef __attribute__((ext_vector_type(4))) float f32x4;
#define MFMA16(a, b, c) __builtin_amdgcn_mfma_f32_16x16x32_bf16((a), (b), (c), 0, 0, 0)

__device__ __forceinline__ float sigm(float x){ return 1.0f/(1.0f + expf(-x)); }
__device__ __forceinline__ float c0f(int p){ return ((float)p/14.0f - 7.0f)/7.0f; }
__device__ __forceinline__ float c1f(int p){ return ((float)(p%14) - 7.0f)/7.0f; }
__device__ __forceinline__ unsigned short f2bf(float x){
  __hip_bfloat16 h = __float2bfloat16(x);
  return *reinterpret_cast<unsigned short*>(&h);
}

// ---------------- weight convert f32 -> bf16, K-padded -----------------------
__global__ void k_cvtpad(const float* __restrict__ src, unsigned short* __restrict__ dst,
                         int rows, int ks, int kd){
  int i = blockIdx.x*256 + threadIdx.x;
  if (i >= rows*kd) return;
  int k = i % kd, r = i / kd;
  dst[i] = (k < ks) ? f2bf(src[r*ks + k]) : (unsigned short)0;
}

// conv weights [oc][cin][3][3] f32 -> wT [s][oc][cpad] bf16
__global__ void k_cvt_wT(const float* __restrict__ w, unsigned short* __restrict__ wT,
                         int cin, int cpad){
  int i = blockIdx.x*256 + threadIdx.x;
  if (i >= 9*128*cpad) return;
  int c = i % cpad; int t = i / cpad; int oc = t % 128; int s = t / 128;
  wT[i] = (c < cin) ? f2bf(w[((size_t)oc*cin + c)*9 + s]) : (unsigned short)0;
}

__global__ void k_bias2(const float* __restrict__ bif, const float* __restrict__ bhf,
                        const float* __restrict__ bib, const float* __restrict__ bhb,
                        float* __restrict__ out){
  int i = blockIdx.x*256 + threadIdx.x;
  if (i >= 8192) return;
  out[i] = (i < 4096) ? (bif[i] + bhf[i]) : (bib[i-4096] + bhb[i-4096]);
}

// ---------------- embedding -> bf16 x[s][b][384] ------------------------------
__global__ void k_embed_bf(const int* __restrict__ que, const float* __restrict__ emb,
                           unsigned short* __restrict__ x){
  int idx = blockIdx.x*256 + threadIdx.x;
  if (idx >= S_*B_*KX) return;
  int e = idx % KX; int sb = idx / KX; int b = sb % B_; int s = sb / B_;
  float v = 0.0f;
  if (e < 300){
    int t = que[b*S_ + s];
    if (t != 0) v = emb[t*300 + e];
  }
  x[idx] = f2bf(v);
}

// ---------------- one LSTM step via MFMA (v4: K-chunk 128) --------------------
// grid (128 unit-tiles of 8, 2 dirs) x 256 thr (4 waves).
// Block tile: M=128 batch x N=32 cols (col = gate*8 + u). Wave w: rows 32w..+32.
// K = 3 x-chunks + 8 h-chunks of 128. A+B LDS dbuf, reg prefetch, 1 barrier/chunk.
__launch_bounds__(256, 1)
__global__ void k_step4(const unsigned short* __restrict__ xbf,
                        const unsigned short* __restrict__ wihc,
                        const unsigned short* __restrict__ whhc,
                        const float* __restrict__ bias2,
                        const unsigned short* __restrict__ hin,
                        unsigned short* __restrict__ hout,
                        float* __restrict__ cst, float* __restrict__ Q, int s){
  const int dir = blockIdx.y;
  const int u0  = blockIdx.x * 8;
  const int tid = threadIdx.x, wave = tid >> 6, lane = tid & 63;
  const int lr = lane & 15, lk = lane >> 4;
  const int xs = dir ? (S_-1-s) : s;
  const unsigned short* xrow = xbf + (size_t)xs*B_*KX;
  const unsigned short* hrow = hin + (size_t)dir*B_*H_;
  const unsigned short* wih = wihc + (size_t)dir*4096*KX;
  const unsigned short* whh = whhc + (size_t)dir*4096*H_;

  __shared__ unsigned short tA[2][128][136];
  __shared__ unsigned short tB[2][32][136];
  __shared__ float sG[128][33];

  // staging: A: thread -> row mA (tid>>1), 64 shorts at (tid&1)*64 (8 short8)
  const int mA = tid >> 1, hA = (tid & 1)*64;
  // B: threads 0..127 -> col colS (tid>>2), 32 shorts at (tid&3)*32 (4 short8)
  const int colS = tid >> 2, kqS = (tid & 3)*32;
  const int wrS = (colS >> 3)*1024 + u0 + (colS & 7);

  // chunk 0 (x-part) straight to LDS
  {
    #pragma unroll
    for (int q = 0; q < 8; ++q)
      *(short8v*)&tA[0][mA][hA + q*8] = *(const short8v*)(xrow + (size_t)mA*KX + hA + q*8);
    if (tid < 128){
      #pragma unroll
      for (int q = 0; q < 4; ++q)
        *(short8v*)&tB[0][colS][kqS + q*8] = *(const short8v*)(wih + (size_t)wrS*KX + kqS + q*8);
    }
  }
  __syncthreads();

  f32x4 acc00{0,0,0,0}, acc01{0,0,0,0}, acc10{0,0,0,0}, acc11{0,0,0,0};
  const int m0 = wave*32 + lr, m1 = wave*32 + 16 + lr;

  for (int ch = 0; ch < 11; ++ch){
    const int cb = ch & 1;
    // prefetch next chunk into regs (issue-early)
    short8v pa[8], pb[4];
    const bool has = (ch + 1) < 11;
    if (has){
      const int nc = ch + 1;
      const unsigned short* sa; int Ka, kb;
      if (nc < 3){ sa = xrow; Ka = KX; kb = nc*128; }
      else       { sa = hrow; Ka = H_; kb = (nc-3)*128; }
      #pragma unroll
      for (int q = 0; q < 8; ++q)
        pa[q] = *(const short8v*)(sa + (size_t)mA*Ka + kb + hA + q*8);
      if (tid < 128){
        const unsigned short* wb = (nc < 3) ? (wih + (size_t)wrS*KX) : (whh + (size_t)wrS*H_);
        #pragma unroll
        for (int q = 0; q < 4; ++q)
          pb[q] = *(const short8v*)(wb + kb + kqS + q*8);
      }
    }
    // MFMA on current chunk: 4 k-frags
    #pragma unroll
    for (int kf = 0; kf < 4; ++kf){
      const int ko = kf*32 + lk*8;
      short8v a0 = *(short8v*)&tA[cb][m0][ko];
      short8v a1 = *(short8v*)&tA[cb][m1][ko];
      short8v b0 = *(short8v*)&tB[cb][lr][ko];
      short8v b1 = *(short8v*)&tB[cb][16 + lr][ko];
      acc00 = MFMA16(a0, b0, acc00); acc01 = MFMA16(a0, b1, acc01);
      acc10 = MFMA16(a1, b0, acc10); acc11 = MFMA16(a1, b1, acc11);
    }
    // write-late
    if (has){
      #pragma unroll
      for (int q = 0; q < 8; ++q) *(short8v*)&tA[cb^1][mA][hA + q*8] = pa[q];
      if (tid < 128){
        #pragma unroll
        for (int q = 0; q < 4; ++q) *(short8v*)&tB[cb^1][colS][kqS + q*8] = pb[q];
      }
    }
    __syncthreads();
  }

  // C/D: row = lk*4+j, col = lr
  #pragma unroll
  for (int j = 0; j < 4; ++j){
    const int rr = lk*4 + j;
    sG[wave*32 + rr][lr]           = acc00[j];
    sG[wave*32 + rr][16 + lr]      = acc01[j];
    sG[wave*32 + 16 + rr][lr]      = acc10[j];
    sG[wave*32 + 16 + rr][16 + lr] = acc11[j];
  }
  __syncthreads();

  const float* bb = bias2 + (size_t)dir*4096;
  float* cc = cst + (size_t)dir*B_*H_;
  unsigned short* ho = hout + (size_t)dir*B_*H_;
  #pragma unroll
  for (int t = 0; t < 4; ++t){
    const int idx = tid + t*256;              // 1024 tasks: 128 m x 8 u
    const int m = idx >> 3, u = idx & 7, ug = u0 + u;
    float gi = sG[m][u]      + bb[ug];
    float gf = sG[m][8+u]    + bb[1024+ug];
    float gg = sG[m][16+u]   + bb[2048+ug];
    float go = sG[m][24+u]   + bb[3072+ug];
    float cold = cc[m*H_ + ug];
    float cn = sigm(gf)*cold + sigm(gi)*tanhf(gg);
    float hn = sigm(go)*tanhf(cn);
    cc[m*H_ + ug] = cn;
    ho[m*H_ + ug] = f2bf(hn);
    Q[((size_t)xs*B_ + m)*2048 + dir*1024 + ug] = hn;
  }
}

// ---------------- qenc L2-normalize (in-place) + enc --------------------------
__global__ void k_qnorm(float* __restrict__ Q, float* __restrict__ enc){
  int sb = blockIdx.x;
  int s = sb >> 7, b = sb & 127;
  float* row = Q + (size_t)sb*2048;
  int tid = threadIdx.x;
  float v[8]; float ss = 0.f;
  #pragma unroll
  for (int i = 0; i < 8; ++i){ v[i] = row[tid*8+i]; ss += v[i]*v[i]; }
  __shared__ float red[256];
  red[tid] = ss; __syncthreads();
  for (int st = 128; st; st >>= 1){
    if (tid < st) red[tid] += red[tid+st];
    __syncthreads();
  }
  float inv = 1.0f / fmaxf(sqrtf(red[0]), 1e-12f);
  #pragma unroll
  for (int i = 0; i < 8; ++i){
    float q = v[i]*inv;
    row[tid*8+i] = q;
    if (s == S_-1) enc[(size_t)b*2048 + tid*8 + i] = q;
  }
}

// ---------------- per-pixel channel sumsq of img ------------------------------
__global__ void k_sqpart(const float* __restrict__ img, float* __restrict__ part){
  int b = blockIdx.x, cq = blockIdx.y;
  int t = threadIdx.x;
  if (t >= P_) return;
  const float* base = img + ((size_t)b*1024 + cq*256)*P_ + t;
  float s = 0.f;
  #pragma unroll 4
  for (int c = 0; c < 256; ++c){ float v = base[c*P_]; s += v*v; }
  part[((size_t)b*4 + cq)*P_ + t] = s;
}

__global__ void k_invnorm(const float* __restrict__ part, float* __restrict__ inv){
  int i = blockIdx.x*256 + threadIdx.x;
  if (i >= B_*P_) return;
  int b = i / P_, p = i % P_;
  float s = part[(b*4+0)*P_+p] + part[(b*4+1)*P_+p]
          + part[(b*4+2)*P_+p] + part[(b*4+3)*P_+p];
  inv[i] = 1.0f / fmaxf(sqrtf(s), 1e-12f);
}

// ---------------- 3x3 conv via MFMA (v3: MLP staging) -------------------------
// grid (128 b, 2 z); block 256 (4 waves). M=128 oc (A=weights from L2),
// N=256 padded 16x16 positions (B=input tile, LDS dbuf), K chunks of 32.
// conv_stage: two register batches of 13/12 independent loads, then cvt+write.
template<int CIN, int MODE>
__device__ __forceinline__ void conv_stage(unsigned short (*__restrict__ tile)[40],
                                           const float* __restrict__ in,
                                           const float* __restrict__ sInv,
                                           int b, int c0, int tid){
  #pragma unroll
  for (int half = 0; half < 2; ++half){
    const int jn = half ? 12 : 13;
    float r[13];
    #pragma unroll
    for (int j = 0; j < 13; ++j){
      if (j >= jn) break;
      int i = tid + (half*13 + j)*256;
      if (i < 6272){
        int c = i / 196, p = i - c*196;
        int cg = c0 + c;
        float v;
        if (MODE == 0){
          if (cg < 1024)       v = in[((size_t)b*1024 + cg)*P_ + p] * sInv[p];
          else if (cg == 1024) v = c0f(p);
          else if (cg == 1025) v = c1f(p);
          else                 v = 0.f;
        } else {
          v = in[((size_t)b*CIN + cg)*P_ + p];
        }
        r[j] = v;
      }
    }
    #pragma unroll
    for (int j = 0; j < 13; ++j){
      if (j >= jn) break;
      int i = tid + (half*13 + j)*256;
      if (i < 6272){
        int c = i / 196, p = i - c*196;
        int py = p / 14;
        tile[(py + 1)*16 + (p - py*14) + 1][c] = f2bf(r[j]);
      }
    }
  }
}

template<int CIN, int MODE>
__launch_bounds__(256, 1)
__global__ void k_conv3m(const float* __restrict__ in, const float* __restrict__ invn,
                         const unsigned short* __restrict__ wT, const float* __restrict__ bias,
                         float* __restrict__ out){
  constexpr int CPAD = (CIN + 31) & ~31;
  constexpr int T = CPAD / 32;
  const int b = blockIdx.x, z = blockIdx.y;
  const int chBeg = (z*T)/2, chEnd = ((z+1)*T)/2;
  const int tid = threadIdx.x, wave = tid >> 6, lane = tid & 63;
  const int lr = lane & 15, lk = lane >> 4;
  const int wfM = wave >> 1, wfN = wave & 1;

  __shared__ unsigned short tile[2][296][40];
  __shared__ float sInv[200];

  for (int i = tid; i < 2*296*40; i += 256) (&tile[0][0][0])[i] = 0;
  if (MODE == 0) for (int i = tid; i < 196; i += 256) sInv[i] = invn[b*196 + i];
  __syncthreads();
  conv_stage<CIN,MODE>(tile[0], in, sInv, b, chBeg*32, tid);
  __syncthreads();

  f32x4 acc[4][8];
  #pragma unroll
  for (int i = 0; i < 4; ++i)
    #pragma unroll
    for (int j = 0; j < 8; ++j) acc[i][j] = f32x4{0,0,0,0};

  for (int ch = chBeg; ch < chEnd; ++ch){
    const int cur = (ch - chBeg) & 1;
    #pragma unroll
    for (int dy = 0; dy < 3; ++dy){
      #pragma unroll
      for (int dx = 0; dx < 3; ++dx){
        const int dlt = dy*16 + dx;
        short8v a[4];
        #pragma unroll
        for (int rf = 0; rf < 4; ++rf)
          a[rf] = *(const short8v*)(wT + ((size_t)((dy*3+dx)*128) + wfM*64 + rf*16 + lr)*CPAD
                                       + ch*32 + lk*8);
        #pragma unroll
        for (int cf = 0; cf < 8; ++cf){
          short8v bf = *(short8v*)&tile[cur][wfN*128 + cf*16 + lr + dlt][lk*8];
          #pragma unroll
          for (int rf = 0; rf < 4; ++rf)
            acc[rf][cf] = MFMA16(a[rf], bf, acc[rf][cf]);
        }
      }
      // hide next-chunk staging under dy=1,2 MFMA groups
      if (dy == 0 && ch + 1 < chEnd)
        conv_stage<CIN,MODE>(tile[cur^1], in, sInv, b, (ch+1)*32, tid);
    }
    __syncthreads();
  }

  // epilogue: C row = oc (lk*4+j), col = pos (lr)
  #pragma unroll
  for (int rf = 0; rf < 4; ++rf){
    #pragma unroll
    for (int j = 0; j < 4; ++j){
      const int oc = wfM*64 + rf*16 + lk*4 + j;
      const float bz = z ? 0.f : bias[oc];
      #pragma unroll
      for (int cf = 0; cf < 8; ++cf){
        const int pos = wfN*128 + cf*16 + lr;
        const int py = pos >> 4, px = pos & 15;
        if (py < 14 && px < 14)
          out[(size_t)z*NE + ((size_t)b*OC_ + oc)*P_ + py*14 + px] = acc[rf][cf][j] + bz;
      }
    }
  }
}

// ---------------- BN stats over 2 partial slabs -------------------------------
__global__ void k_bnstats(const float* __restrict__ t, float* __restrict__ stats){
  int o = blockIdx.x;
  int tid = threadIdx.x;
  float s = 0.f, s2 = 0.f;
  #pragma unroll 4
  for (int i = tid; i < B_*P_; i += 256){
    int b = i / P_, p = i - (i/P_)*P_;
    size_t off = ((size_t)b*OC_ + o)*P_ + p;
    float v = t[off] + t[off + NE];
    s += v; s2 += v*v;
  }
  __shared__ float r1[256], r2[256];
  r1[tid] = s; r2[tid] = s2; __syncthreads();
  for (int st = 128; st; st >>= 1){
    if (tid < st){ r1[tid] += r1[tid+st]; r2[tid] += r2[tid+st]; }
    __syncthreads();
  }
  if (tid == 0){
    float n = (float)(B_*P_);
    float m = r1[0] / n;
    float var = r2[0] / n - m*m;
    stats[o*2]   = m;
    stats[o*2+1] = rsqrtf(var + 1e-5f);
  }
}

// ---------------- BN apply + relu (+ optional residual add) -------------------
template<bool ADD>
__global__ void k_bnapply(const float* __restrict__ t, const float* __restrict__ stats,
                          const float* __restrict__ g, const float* __restrict__ bb,
                          const float* __restrict__ addsrc, float* __restrict__ out){
  int idx = blockIdx.x*256 + threadIdx.x;
  if (idx >= NE) return;
  int o = (idx / P_) % OC_;
  float m = stats[o*2], is = stats[o*2+1];
  float x = t[idx] + t[idx + NE];
  float v = g[o]*(x-m)*is + bb[o];
  v = fmaxf(v, 0.f);
  if (ADD) v += addsrc[idx];
  out[idx] = v;
}

// ---------------- 1x1 conv over [v(128) | coord(2)] + bias + relu -------------
__launch_bounds__(256)
__global__ void k_conv1x1(const float* __restrict__ vin, const float* __restrict__ w,
                          const float* __restrict__ bias, float* __restrict__ out){
  const int b  = blockIdx.x;
  const int o0 = blockIdx.y * 64;
  const int tid = threadIdx.x;
  const int olane = tid & 63, pg = tid >> 6;
  const int o = o0 + olane;

  __shared__ float sV[32][196];
  __shared__ float sW[64][33];

  float acc[49];
  #pragma unroll
  for (int p = 0; p < 49; ++p) acc[p] = 0.f;

  for (int ch = 0; ch < 128; ch += 32){
    __syncthreads();
    for (int i = tid; i < 32*196; i += 256){
      int c = i / 196, p = i - c*196;
      sV[c][p] = vin[((size_t)b*128 + ch + c)*P_ + p];
    }
    for (int i = tid; i < 64*32; i += 256){
      int ol = i >> 5, c = i & 31;
      sW[ol][c] = w[(size_t)(o0+ol)*130 + ch + c];
    }
    __syncthreads();
    for (int c = 0; c < 32; ++c){
      float wv = sW[olane][c];
      #pragma unroll
      for (int p = 0; p < 49; ++p) acc[p] += sV[c][pg*49 + p] * wv;
    }
  }
  float w0 = w[(size_t)o*130 + 128], w1 = w[(size_t)o*130 + 129], bz = bias[o];
  #pragma unroll
  for (int p = 0; p < 49; ++p){
    int pp = pg*49 + p;
    float v = acc[p] + w0*c0f(pp) + w1*c1f(pp) + bz;
    out[((size_t)b*128 + o)*P_ + pp] = fmaxf(v, 0.f);
  }
}

} // namespace

// ---------------------------------------------------------------------------
extern "C" void kernel_launch(void* const* d_in, const int* in_sizes, int n_in,
                              void* d_out, int out_size, void* d_ws, size_t ws_size,
                              hipStream_t stream){
  (void)in_sizes; (void)n_in; (void)out_size; (void)ws_size;
  const int*   que  = (const int*)  d_in[0];
  const float* img  = (const float*)d_in[1];
  const float* emb  = (const float*)d_in[2];
  const float* wihf = (const float*)d_in[3];
  const float* whhf = (const float*)d_in[4];
  const float* bihf = (const float*)d_in[5];
  const float* bhhf = (const float*)d_in[6];
  const float* wihb = (const float*)d_in[7];
  const float* whhb = (const float*)d_in[8];
  const float* bihb = (const float*)d_in[9];
  const float* bhhb = (const float*)d_in[10];
  const float* convw = (const float*)d_in[11];
  const float* convb = (const float*)d_in[12];
  const float* bng  = (const float*)d_in[13];
  const float* bnb  = (const float*)d_in[14];
  const float* r1c1w = (const float*)d_in[15];
  const float* r1c1b = (const float*)d_in[16];
  const float* r1c2w = (const float*)d_in[17];
  const float* r1c2b = (const float*)d_in[18];
  const float* r1bng = (const float*)d_in[19];
  const float* r1bnb = (const float*)d_in[20];
  const float* r2c1w = (const float*)d_in[21];
  const float* r2c1b = (const float*)d_in[22];
  const float* r2c2w = (const float*)d_in[23];
  const float* r2c2b = (const float*)d_in[24];
  const float* r2bng = (const float*)d_in[25];
  const float* r2bnb = (const float*)d_in[26];

  float* out  = (float*)d_out;
  float* enc  = out;                        // 128*2048
  float* Q    = out + 262144;               // 32*128*2048
  float* vout = out + 262144 + 8388608;     // 128*128*196

  // ------ workspace layout (f32 units) ----------------------------------------
  float* ws = (float*)d_ws;
  unsigned short* xbf  = (unsigned short*)ws;            // 32*128*384 bf16
  float* p1 = ws + 786432;
  unsigned short* wihc = (unsigned short*)p1;            // 2*4096*384 bf16
  float* p2 = p1 + 1572864;
  unsigned short* whhc = (unsigned short*)p2;            // 2*4096*1024 bf16
  float* p3 = p2 + 4194304;
  float* bias2 = p3;                                     // 2*4096
  float* p4 = p3 + 8192;
  unsigned short* hstate = (unsigned short*)p4;          // 2par*2dir*128*1024 bf16
  float* p5 = p4 + 262144;
  float* cstate = p5;                                    // 2*128*1024
  float* p6 = p5 + 262144;
  float* part = p6;                                      // 128*4*196
  float* invn = p6 + 100352;                             // 128*196
  float* bufA = invn + 25088;                            // NE
  float* bufB = bufA + NE;                               // NE
  float* convOut = bufB + NE;                            // 2*NE partial slabs
  float* p7 = convOut + 2*(size_t)NE;
  float* stats = p7;                                     // 256
  float* p8 = p7 + 256;
  unsigned short* wTc  = (unsigned short*)p8;            // 9*128*1056 bf16
  float* p9 = p8 + 608256;
  unsigned short* wTr1 = (unsigned short*)p9;            // 9*128*128 bf16
  float* p10 = p9 + 73728;
  unsigned short* wTr2 = (unsigned short*)p10;           // 9*128*128 bf16

  hipMemsetAsync(hstate, 0, (size_t)(262144 + 262144)*sizeof(float), stream);

  // ------ conversions ---------------------------------------------------------
  k_cvtpad<<<6144, 256, 0, stream>>>(wihf, wihc,                     4096, 300, KX);
  k_cvtpad<<<6144, 256, 0, stream>>>(wihb, wihc + (size_t)4096*KX,   4096, 300, KX);
  k_cvtpad<<<16384,256, 0, stream>>>(whhf, whhc,                     4096, 1024, 1024);
  k_cvtpad<<<16384,256, 0, stream>>>(whhb, whhc + (size_t)4096*1024, 4096, 1024, 1024);
  k_bias2<<<32, 256, 0, stream>>>(bihf, bhhf, bihb, bhhb, bias2);
  k_embed_bf<<<6144, 256, 0, stream>>>(que, emb, xbf);
  k_cvt_wT<<<(9*128*1056 + 255)/256, 256, 0, stream>>>(convw, wTc, 1026, 1056);
  k_cvt_wT<<<(9*128*128 + 255)/256, 256, 0, stream>>>(r1c2w, wTr1, 128, 128);
  k_cvt_wT<<<(9*128*128 + 255)/256, 256, 0, stream>>>(r2c2w, wTr2, 128, 128);

  // ------ bi-LSTM -------------------------------------------------------------
  for (int s = 0; s < 32; ++s){
    unsigned short* hin  = hstate + (size_t)(s & 1)*262144;
    unsigned short* hout = hstate + (size_t)((s & 1)^1)*262144;
    k_step4<<<dim3(128,2), 256, 0, stream>>>(xbf, wihc, whhc, bias2,
                                             hin, hout, cstate, Q, s);
  }
  k_qnorm<<<4096, 256, 0, stream>>>(Q, enc);

  // ------ image branch --------------------------------------------------------
  k_sqpart<<<dim3(128,4), 256, 0, stream>>>(img, part);
  k_invnorm<<<(25088+255)/256, 256, 0, stream>>>(part, invn);

  k_conv3m<1026,0><<<dim3(128,2), 256, 0, stream>>>(img, invn, wTc, convb, convOut);
  k_bnstats<<<128, 256, 0, stream>>>(convOut, stats);
  k_bnapply<false><<<(NE+255)/256, 256, 0, stream>>>(convOut, stats, bng, bnb, bufA, bufA);

  // res block 1: bufA(v) -> bufB(v1) -> convOut -> bufA(v2+v1)
  k_conv1x1<<<dim3(128,2), 256, 0, stream>>>(bufA, r1c1w, r1c1b, bufB);
  k_conv3m<128,1><<<dim3(128,2), 256, 0, stream>>>(bufB, invn, wTr1, r1c2b, convOut);
  k_bnstats<<<128, 256, 0, stream>>>(convOut, stats);
  k_bnapply<true><<<(NE+255)/256, 256, 0, stream>>>(convOut, stats, r1bng, r1bnb, bufB, bufA);

  // res block 2: bufA -> bufB(v1) -> convOut -> vout
  k_conv1x1<<<dim3(128,2), 256, 0, stream>>>(bufA, r2c1w, r2c1b, bufB);
  k_conv3m<128,1><<<dim3(128,2), 256, 0, stream>>>(bufB, invn, wTr2, r2c2b, convOut);
  k_bnstats<<<128, 256, 0, stream>>>(convOut, stats);
  k_bnapply<true><<<(NE+255)/256, 256, 0, stream>>>(convOut, stats, r2bng, r2bnb, bufB, vout);
}